// Round 6
// baseline (513.265 us; speedup 1.0000x reference)
//
#include <hip/hip_runtime.h>

#define N_NODES 100000
#define N_EDGES 1600000
#define HD 128
#define SLOPE 0.2f
#define TMR 128   // rows per gemm1 block
#define PP 132    // LDS pitch (floats)
#define NBLK 391  // ceil(N_NODES/256)

// ---------------------------------------------------------------------------
// K1: xp1 = emb[h] @ W1 — LDS-tiled, 8x8 register micro-tiles (FMA:LDS = 16:1
// per instr, vs 4:1 in the 4x4 version that was LDS-throughput-bound).
// X staged k-major (transposed scalar writes, 2-way spread = free); W row-major.
// Compute reads rotate k by (cg>>2)&3 to break the 4-way cg bank aliasing.
// Fused: es1/ed1 dots and denom1 = w_self = exp(leaky(es+ed)).
// ---------------------------------------------------------------------------
__global__ __launch_bounds__(256) void gemm1_kernel(
    const int* __restrict__ h,
    const float* __restrict__ emb,
    const float* __restrict__ W1,
    const float* __restrict__ a_src1,
    const float* __restrict__ a_dst1,
    float* __restrict__ xp1,
    float* __restrict__ es1,
    float* __restrict__ ed1,
    float* __restrict__ denom1)
{
    __shared__ float Xc[32 * PP];   // 16.9 KB: X chunk, k-major: Xc[kk][r]
    __shared__ float Wc[32 * PP];   // 16.9 KB: W chunk, row-major: Wc[kk][c]

    const int tid  = threadIdx.x;
    const int row0 = blockIdx.x * TMR;

    const int cg = tid & 15;        // col-group: cols cg*8..+7
    const int rg = tid >> 4;        // row-group: rows rg*8..+7
    const int c0 = cg * 8;
    const int r0 = rg * 8;
    const int jrot = (cg >> 2) & 3;

    // staging coords
    const int sr   = tid >> 1;                 // X: row 0..127
    const int shalf = (tid & 1) * 16;          // X: k offset 0 or 16
    const int grow = (row0 + sr < N_NODES) ? (row0 + sr) : (N_NODES - 1);
    const int hrow = h[grow];
    const int wkr  = tid >> 3;                 // W: k row 0..31
    const int wcc  = (tid & 7) * 16;           // W: col 0..112

    float acc[8][8];
    #pragma unroll
    for (int r = 0; r < 8; ++r)
        #pragma unroll
        for (int c = 0; c < 8; ++c) acc[r][c] = 0.f;

    for (int kc = 0; kc < HD; kc += 32) {
        __syncthreads();
        // ---- stage X chunk transposed: thread loads 16 k's of one row ----
        {
            const float* src = emb + (size_t)hrow * HD + kc + shalf;
            #pragma unroll
            for (int j = 0; j < 4; ++j) {
                const float4 v = *(const float4*)(src + 4 * j);
                Xc[(shalf + 4 * j + 0) * PP + sr] = v.x;
                Xc[(shalf + 4 * j + 1) * PP + sr] = v.y;
                Xc[(shalf + 4 * j + 2) * PP + sr] = v.z;
                Xc[(shalf + 4 * j + 3) * PP + sr] = v.w;
            }
        }
        // ---- stage W chunk row-major (pitch PP) ----
        {
            const float* src = W1 + (size_t)(kc + wkr) * HD + wcc;
            float* dst = Wc + wkr * PP + wcc;
            #pragma unroll
            for (int j = 0; j < 4; ++j)
                *(float4*)(dst + 4 * j) = *(const float4*)(src + 4 * j);
        }
        __syncthreads();

        #pragma unroll
        for (int kk = 0; kk < 32; kk += 4) {
            #pragma unroll
            for (int t = 0; t < 4; ++t) {
                const int k = kk + ((t + jrot) & 3);
                const float4 x0 = *(const float4*)(Xc + k * PP + r0);
                const float4 x1 = *(const float4*)(Xc + k * PP + r0 + 4);
                const float4 w0 = *(const float4*)(Wc + k * PP + c0);
                const float4 w1 = *(const float4*)(Wc + k * PP + c0 + 4);
                const float xr[8] = {x0.x, x0.y, x0.z, x0.w, x1.x, x1.y, x1.z, x1.w};
                const float wr[8] = {w0.x, w0.y, w0.z, w0.w, w1.x, w1.y, w1.z, w1.w};
                #pragma unroll
                for (int r = 0; r < 8; ++r)
                    #pragma unroll
                    for (int c = 0; c < 8; ++c)
                        acc[r][c] += xr[r] * wr[c];
            }
        }
    }

    // ---- fused epilogue: attention dots + reduce over cg lanes ----
    float as[8], ad[8];
    *(float4*)(as)     = *(const float4*)(a_src1 + c0);
    *(float4*)(as + 4) = *(const float4*)(a_src1 + c0 + 4);
    *(float4*)(ad)     = *(const float4*)(a_dst1 + c0);
    *(float4*)(ad + 4) = *(const float4*)(a_dst1 + c0 + 4);

    float ps[8], pd[8];
    #pragma unroll
    for (int r = 0; r < 8; ++r) {
        float s = 0.f, d = 0.f;
        #pragma unroll
        for (int c = 0; c < 8; ++c) { s += acc[r][c] * as[c]; d += acc[r][c] * ad[c]; }
        ps[r] = s; pd[r] = d;
    }
    #pragma unroll
    for (int m = 1; m < 16; m <<= 1) {
        #pragma unroll
        for (int r = 0; r < 8; ++r) {
            ps[r] += __shfl_xor(ps[r], m, 64);
            pd[r] += __shfl_xor(pd[r], m, 64);
        }
    }

    #pragma unroll
    for (int r = 0; r < 8; ++r) {
        const int row = row0 + r0 + r;
        if (row < N_NODES) {
            float* dst = xp1 + (size_t)row * HD + c0;
            *(float4*)(dst)     = make_float4(acc[r][0], acc[r][1], acc[r][2], acc[r][3]);
            *(float4*)(dst + 4) = make_float4(acc[r][4], acc[r][5], acc[r][6], acc[r][7]);
            if (cg == 0) {
                const float s = ps[r] + pd[r];
                const float l = s > 0.f ? s : SLOPE * s;
                es1[row] = ps[r];
                ed1[row] = pd[r];
                denom1[row] = __expf(l);
            }
        }
    }
}

// ---------------------------------------------------------------------------
// zero deg/fill/qcount
// ---------------------------------------------------------------------------
__global__ __launch_bounds__(256) void zero_kernel(
    int* __restrict__ deg, int* __restrict__ fill, int* __restrict__ qcount)
{
    const int i = blockIdx.x * 256 + threadIdx.x;
    if (i < N_NODES) { deg[i] = 0; fill[i] = 0; }
    if (i == 0) *qcount = 0;
}

// ---------------------------------------------------------------------------
// Pass A: gate + deg histogram + wave-aggregated compaction into (src,dst,w).
// ---------------------------------------------------------------------------
__global__ __launch_bounds__(256) void edgeA_kernel(
    const int* __restrict__ ei, const int* __restrict__ nt,
    const float* __restrict__ es1, const float* __restrict__ ed1,
    int* __restrict__ deg, int* __restrict__ qcount,
    int* __restrict__ qsrc, int* __restrict__ qdst, float* __restrict__ qw)
{
    const int e = blockIdx.x * 256 + threadIdx.x;
    const int lane = threadIdx.x & 63;
    const int src = ei[e];
    const int dst = ei[N_EDGES + e];
    const bool active = (nt[src] | nt[dst]) == 0;

    const unsigned long long bal = __ballot(active);
    if (bal == 0ull) return;
    const int leader = (int)__ffsll((long long)bal) - 1;
    int base = 0;
    if (lane == leader) base = atomicAdd(qcount, (int)__popcll(bal));
    base = __shfl(base, leader, 64);

    if (active) {
        atomicAdd(deg + dst, 1);
        const float logit = es1[src] + ed1[dst];
        const float l = logit > 0.f ? logit : SLOPE * logit;
        const int slot = base + (int)__popcll(bal & ((1ull << lane) - 1ull));
        qsrc[slot] = src;
        qdst[slot] = dst;
        qw[slot] = __expf(l);
    }
}

// ---------------------------------------------------------------------------
// scans: block sums -> block scan -> rowptr
// ---------------------------------------------------------------------------
__global__ __launch_bounds__(256) void bsum_kernel(
    const int* __restrict__ deg, int* __restrict__ bsum)
{
    __shared__ int wsum[4];
    const int i = blockIdx.x * 256 + threadIdx.x;
    int v = (i < N_NODES) ? deg[i] : 0;
    #pragma unroll
    for (int off = 32; off > 0; off >>= 1) v += __shfl_down(v, off, 64);
    if ((threadIdx.x & 63) == 0) wsum[threadIdx.x >> 6] = v;
    __syncthreads();
    if (threadIdx.x == 0) bsum[blockIdx.x] = wsum[0] + wsum[1] + wsum[2] + wsum[3];
}

__global__ __launch_bounds__(512) void bscan_kernel(
    const int* __restrict__ bsum, int* __restrict__ bscan, int* __restrict__ rowptr)
{
    __shared__ int s[512];
    const int t = threadIdx.x;
    const int v = (t < NBLK) ? bsum[t] : 0;
    s[t] = v;
    __syncthreads();
    #pragma unroll
    for (int off = 1; off < 512; off <<= 1) {
        const int u = (t >= off) ? s[t - off] : 0;
        __syncthreads();
        s[t] += u;
        __syncthreads();
    }
    if (t < NBLK) bscan[t] = s[t] - v;
    if (t == 0) rowptr[N_NODES] = s[NBLK - 1];
}

__global__ __launch_bounds__(256) void rowptr_kernel(
    const int* __restrict__ deg, const int* __restrict__ bscan, int* __restrict__ rowptr)
{
    __shared__ int s[256];
    const int t = threadIdx.x;
    const int i = blockIdx.x * 256 + t;
    const int v = (i < N_NODES) ? deg[i] : 0;
    s[t] = v;
    __syncthreads();
    #pragma unroll
    for (int off = 1; off < 256; off <<= 1) {
        const int u = (t >= off) ? s[t - off] : 0;
        __syncthreads();
        s[t] += u;
        __syncthreads();
    }
    if (i < N_NODES) rowptr[i] = bscan[blockIdx.x] + s[t] - v;
}

// ---------------------------------------------------------------------------
// Pass B: place compacted edges into CSR slots (only ~11% of E items).
// ---------------------------------------------------------------------------
__global__ __launch_bounds__(256) void scatterB_kernel(
    const int* __restrict__ qsrc, const int* __restrict__ qdst,
    const float* __restrict__ qw, const int* __restrict__ qcount,
    const int* __restrict__ rowptr, int* __restrict__ fill,
    int* __restrict__ esrc, float* __restrict__ ew)
{
    const int qn = *qcount;
    const int stride = gridDim.x * 256;
    for (int i = blockIdx.x * 256 + threadIdx.x; i < qn; i += stride) {
        const int dst = qdst[i];
        const int slot = rowptr[dst] + atomicAdd(fill + dst, 1);
        esrc[slot] = qsrc[i];
        ew[slot] = qw[i];
    }
}

// ---------------------------------------------------------------------------
// Gather layer 1 (one wave per node) + normalize + b1 + ReLU + W2 GEMV -> xp2.
// ---------------------------------------------------------------------------
__global__ __launch_bounds__(256) void gather1_kernel(
    const float* __restrict__ xp1, const float* __restrict__ denom1,
    const int* __restrict__ rowptr, const int* __restrict__ esrc,
    const float* __restrict__ ew,
    const float* __restrict__ b1, const float* __restrict__ W2,
    float* __restrict__ xp2)
{
    const int wid = threadIdx.x >> 6;
    const int lane = threadIdx.x & 63;
    const int i = blockIdx.x * 4 + wid;
    if (i >= N_NODES) return;

    const int begin = rowptr[i];
    const int end   = rowptr[i + 1];
    const float wself = denom1[i];

    const float2 xs = ((const float2*)(xp1 + (size_t)i * HD))[lane];
    float a0 = wself * xs.x, a1 = wself * xs.y;
    float denom = wself;

    int sN = 0; float wN = 0.f;
    if (begin < end) { sN = esrc[begin]; wN = ew[begin]; }
    for (int j = begin; j < end; ++j) {
        const int s = sN; const float w = wN;
        if (j + 1 < end) { sN = esrc[j + 1]; wN = ew[j + 1]; }
        const float2 v = ((const float2*)(xp1 + (size_t)s * HD))[lane];
        a0 += w * v.x;
        a1 += w * v.y;
        denom += w;
    }

    const float inv = 1.f / denom;
    const float o0 = fmaxf(a0 * inv + b1[2 * lane],     0.f);
    const float o1 = fmaxf(a1 * inv + b1[2 * lane + 1], 0.f);

    float part = o0 * W2[2 * lane] + o1 * W2[2 * lane + 1];
    #pragma unroll
    for (int off = 32; off > 0; off >>= 1) part += __shfl_down(part, off, 64);
    if (lane == 0) xp2[i] = part;
}

// ---------------------------------------------------------------------------
// Layer 2 over scalars (one thread per node): reuse the same CSR.
// ---------------------------------------------------------------------------
__global__ __launch_bounds__(256) void final2_kernel(
    const float* __restrict__ xp2, const int* __restrict__ rowptr,
    const int* __restrict__ esrc,
    const float* __restrict__ a_src2, const float* __restrict__ a_dst2,
    const float* __restrict__ b2, float* __restrict__ out)
{
    const int i = blockIdx.x * 256 + threadIdx.x;
    if (i >= N_NODES) return;

    const float as = a_src2[0], ad = a_dst2[0];
    const float xi = xp2[i];
    const float s0 = (as + ad) * xi;
    const float l0 = s0 > 0.f ? s0 : SLOPE * s0;
    const float wself = __expf(l0);

    float denom = wself, num = wself * xi;
    const int end = rowptr[i + 1];
    for (int j = rowptr[i]; j < end; ++j) {
        const float xsv = xp2[esrc[j]];
        const float lg = as * xsv + ad * xi;
        const float ll = lg > 0.f ? lg : SLOPE * lg;
        const float w = __expf(ll);
        denom += w;
        num += w * xsv;
    }
    out[i] = num / denom + b2[0];
}

extern "C" void kernel_launch(void* const* d_in, const int* in_sizes, int n_in,
                              void* d_out, int out_size, void* d_ws, size_t ws_size,
                              hipStream_t stream)
{
    const int* h   = (const int*)d_in[0];
    const int* ei  = (const int*)d_in[1];
    const int* nt  = (const int*)d_in[2];
    const float* emb    = (const float*)d_in[3];
    const float* W1     = (const float*)d_in[4];
    const float* a_src1 = (const float*)d_in[5];
    const float* a_dst1 = (const float*)d_in[6];
    const float* b1     = (const float*)d_in[7];
    const float* W2     = (const float*)d_in[8];
    const float* a_src2 = (const float*)d_in[9];
    const float* a_dst2 = (const float*)d_in[10];
    const float* b2     = (const float*)d_in[11];
    float* out = (float*)d_out;

    char* ws = (char*)d_ws;
    size_t off = 0;
    float* xp1    = (float*)(ws + off); off += (size_t)N_NODES * HD * sizeof(float);
    float* es1    = (float*)(ws + off); off += (size_t)N_NODES * sizeof(float);
    float* ed1    = (float*)(ws + off); off += (size_t)N_NODES * sizeof(float);
    float* denom1 = (float*)(ws + off); off += (size_t)N_NODES * sizeof(float);
    float* xp2    = (float*)(ws + off); off += (size_t)N_NODES * sizeof(float);
    int*   deg    = (int*)(ws + off);   off += (size_t)N_NODES * sizeof(int);
    int*   fill   = (int*)(ws + off);   off += (size_t)N_NODES * sizeof(int);
    int*   rowptr = (int*)(ws + off);   off += ((size_t)N_NODES + 1) * sizeof(int);
    int*   bsum   = (int*)(ws + off);   off += (size_t)NBLK * sizeof(int);
    int*   bscan  = (int*)(ws + off);   off += (size_t)NBLK * sizeof(int);
    int*   qcount = (int*)(ws + off);   off += 64;  // keep alignment
    int*   qsrc   = (int*)(ws + off);   off += (size_t)N_EDGES * sizeof(int);
    int*   qdst   = (int*)(ws + off);   off += (size_t)N_EDGES * sizeof(int);
    float* qw     = (float*)(ws + off); off += (size_t)N_EDGES * sizeof(float);
    int*   esrc   = (int*)(ws + off);   off += (size_t)N_EDGES * sizeof(int);
    float* ew     = (float*)(ws + off); off += (size_t)N_EDGES * sizeof(float);

    zero_kernel<<<NBLK, 256, 0, stream>>>(deg, fill, qcount);
    gemm1_kernel<<<(N_NODES + TMR - 1) / TMR, 256, 0, stream>>>(
        h, emb, W1, a_src1, a_dst1, xp1, es1, ed1, denom1);
    edgeA_kernel<<<N_EDGES / 256, 256, 0, stream>>>(
        ei, nt, es1, ed1, deg, qcount, qsrc, qdst, qw);
    bsum_kernel<<<NBLK, 256, 0, stream>>>(deg, bsum);
    bscan_kernel<<<1, 512, 0, stream>>>(bsum, bscan, rowptr);
    rowptr_kernel<<<NBLK, 256, 0, stream>>>(deg, bscan, rowptr);
    scatterB_kernel<<<1024, 256, 0, stream>>>(
        qsrc, qdst, qw, qcount, rowptr, fill, esrc, ew);
    gather1_kernel<<<(N_NODES + 3) / 4, 256, 0, stream>>>(
        xp1, denom1, rowptr, esrc, ew, b1, W2, xp2);
    final2_kernel<<<NBLK, 256, 0, stream>>>(
        xp2, rowptr, esrc, a_src2, a_dst2, b2, out);
}

// Round 7
// 245.020 us; speedup vs baseline: 2.0948x; 2.0948x over previous
//
#include <hip/hip_runtime.h>

#define N_NODES 100000
#define N_EDGES 1600000
#define HD 128
#define SLOPE 0.2f
#define TMR 128   // rows per gemm1 block
#define PP 132    // LDS pitch (floats)
#define NBLK 391  // ceil(N_NODES/256)
#define EBLK (N_EDGES / 256)   // 6250 edge blocks

// ---------------------------------------------------------------------------
// K1: xp1 = emb[h] @ W1 — LDS-tiled, 8x8 register micro-tiles.
// X staged k-major; W row-major; k-rotation breaks cg bank aliasing.
// Fused: es1/ed1 dots and denom1 = w_self = exp(leaky(es+ed)).
// ---------------------------------------------------------------------------
__global__ __launch_bounds__(256) void gemm1_kernel(
    const int* __restrict__ h,
    const float* __restrict__ emb,
    const float* __restrict__ W1,
    const float* __restrict__ a_src1,
    const float* __restrict__ a_dst1,
    float* __restrict__ xp1,
    float* __restrict__ es1,
    float* __restrict__ ed1,
    float* __restrict__ denom1)
{
    __shared__ float Xc[32 * PP];   // X chunk, k-major: Xc[kk][r]
    __shared__ float Wc[32 * PP];   // W chunk, row-major: Wc[kk][c]

    const int tid  = threadIdx.x;
    const int row0 = blockIdx.x * TMR;

    const int cg = tid & 15;
    const int rg = tid >> 4;
    const int c0 = cg * 8;
    const int r0 = rg * 8;
    const int jrot = (cg >> 2) & 3;

    const int sr    = tid >> 1;
    const int shalf = (tid & 1) * 16;
    const int grow = (row0 + sr < N_NODES) ? (row0 + sr) : (N_NODES - 1);
    const int hrow = h[grow];
    const int wkr  = tid >> 3;
    const int wcc  = (tid & 7) * 16;

    float acc[8][8];
    #pragma unroll
    for (int r = 0; r < 8; ++r)
        #pragma unroll
        for (int c = 0; c < 8; ++c) acc[r][c] = 0.f;

    for (int kc = 0; kc < HD; kc += 32) {
        __syncthreads();
        {
            const float* src = emb + (size_t)hrow * HD + kc + shalf;
            #pragma unroll
            for (int j = 0; j < 4; ++j) {
                const float4 v = *(const float4*)(src + 4 * j);
                Xc[(shalf + 4 * j + 0) * PP + sr] = v.x;
                Xc[(shalf + 4 * j + 1) * PP + sr] = v.y;
                Xc[(shalf + 4 * j + 2) * PP + sr] = v.z;
                Xc[(shalf + 4 * j + 3) * PP + sr] = v.w;
            }
        }
        {
            const float* src = W1 + (size_t)(kc + wkr) * HD + wcc;
            float* dst = Wc + wkr * PP + wcc;
            #pragma unroll
            for (int j = 0; j < 4; ++j)
                *(float4*)(dst + 4 * j) = *(const float4*)(src + 4 * j);
        }
        __syncthreads();

        #pragma unroll
        for (int kk = 0; kk < 32; kk += 4) {
            #pragma unroll
            for (int t = 0; t < 4; ++t) {
                const int k = kk + ((t + jrot) & 3);
                const float4 x0 = *(const float4*)(Xc + k * PP + r0);
                const float4 x1 = *(const float4*)(Xc + k * PP + r0 + 4);
                const float4 w0 = *(const float4*)(Wc + k * PP + c0);
                const float4 w1 = *(const float4*)(Wc + k * PP + c0 + 4);
                const float xr[8] = {x0.x, x0.y, x0.z, x0.w, x1.x, x1.y, x1.z, x1.w};
                const float wr[8] = {w0.x, w0.y, w0.z, w0.w, w1.x, w1.y, w1.z, w1.w};
                #pragma unroll
                for (int r = 0; r < 8; ++r)
                    #pragma unroll
                    for (int c = 0; c < 8; ++c)
                        acc[r][c] += xr[r] * wr[c];
            }
        }
    }

    float as[8], ad[8];
    *(float4*)(as)     = *(const float4*)(a_src1 + c0);
    *(float4*)(as + 4) = *(const float4*)(a_src1 + c0 + 4);
    *(float4*)(ad)     = *(const float4*)(a_dst1 + c0);
    *(float4*)(ad + 4) = *(const float4*)(a_dst1 + c0 + 4);

    float ps[8], pd[8];
    #pragma unroll
    for (int r = 0; r < 8; ++r) {
        float s = 0.f, d = 0.f;
        #pragma unroll
        for (int c = 0; c < 8; ++c) { s += acc[r][c] * as[c]; d += acc[r][c] * ad[c]; }
        ps[r] = s; pd[r] = d;
    }
    #pragma unroll
    for (int m = 1; m < 16; m <<= 1) {
        #pragma unroll
        for (int r = 0; r < 8; ++r) {
            ps[r] += __shfl_xor(ps[r], m, 64);
            pd[r] += __shfl_xor(pd[r], m, 64);
        }
    }

    #pragma unroll
    for (int r = 0; r < 8; ++r) {
        const int row = row0 + r0 + r;
        if (row < N_NODES) {
            float* dst = xp1 + (size_t)row * HD + c0;
            *(float4*)(dst)     = make_float4(acc[r][0], acc[r][1], acc[r][2], acc[r][3]);
            *(float4*)(dst + 4) = make_float4(acc[r][4], acc[r][5], acc[r][6], acc[r][7]);
            if (cg == 0) {
                const float s = ps[r] + pd[r];
                const float l = s > 0.f ? s : SLOPE * s;
                es1[row] = ps[r];
                ed1[row] = pd[r];
                denom1[row] = __expf(l);
            }
        }
    }
}

__global__ __launch_bounds__(256) void zero_kernel(
    int* __restrict__ deg, int* __restrict__ fill)
{
    const int i = blockIdx.x * 256 + threadIdx.x;
    if (i < N_NODES) { deg[i] = 0; fill[i] = 0; }
}

// ---------------------------------------------------------------------------
// Pass A: gate + deg histogram + BLOCK-LOCAL compaction into private segment
// q[blockIdx*256 ...]. No shared counters: ballot + LDS wave-prefix, plain
// store of blockCount. (Round-6's single global ticket counter serialized
// the whole GPU at one L2 address — 293 us.)
// ---------------------------------------------------------------------------
__global__ __launch_bounds__(256) void edgeA_kernel(
    const int* __restrict__ ei, const int* __restrict__ nt,
    const float* __restrict__ es1, const float* __restrict__ ed1,
    int* __restrict__ deg, int* __restrict__ blockCount,
    int* __restrict__ qsrc, int* __restrict__ qdst, float* __restrict__ qw)
{
    __shared__ int wcnt[4];
    const int e = blockIdx.x * 256 + threadIdx.x;
    const int wid = threadIdx.x >> 6;
    const int lane = threadIdx.x & 63;

    const int src = ei[e];
    const int dst = ei[N_EDGES + e];
    const bool active = (nt[src] | nt[dst]) == 0;

    const unsigned long long bal = __ballot(active);
    if (lane == 0) wcnt[wid] = (int)__popcll(bal);
    __syncthreads();
    const int c0w = wcnt[0], c1w = wcnt[1], c2w = wcnt[2], c3w = wcnt[3];
    if (threadIdx.x == 0) blockCount[blockIdx.x] = c0w + c1w + c2w + c3w;

    if (active) {
        int base = 0;
        if (wid > 0) base += c0w;
        if (wid > 1) base += c1w;
        if (wid > 2) base += c2w;
        atomicAdd(deg + dst, 1);
        const float logit = es1[src] + ed1[dst];
        const float l = logit > 0.f ? logit : SLOPE * logit;
        const int slot = blockIdx.x * 256 + base +
                         (int)__popcll(bal & ((1ull << lane) - 1ull));
        qsrc[slot] = src;
        qdst[slot] = dst;
        qw[slot] = __expf(l);
    }
}

// ---------------------------------------------------------------------------
// scans: block sums -> block scan -> rowptr
// ---------------------------------------------------------------------------
__global__ __launch_bounds__(256) void bsum_kernel(
    const int* __restrict__ deg, int* __restrict__ bsum)
{
    __shared__ int wsum[4];
    const int i = blockIdx.x * 256 + threadIdx.x;
    int v = (i < N_NODES) ? deg[i] : 0;
    #pragma unroll
    for (int off = 32; off > 0; off >>= 1) v += __shfl_down(v, off, 64);
    if ((threadIdx.x & 63) == 0) wsum[threadIdx.x >> 6] = v;
    __syncthreads();
    if (threadIdx.x == 0) bsum[blockIdx.x] = wsum[0] + wsum[1] + wsum[2] + wsum[3];
}

__global__ __launch_bounds__(512) void bscan_kernel(
    const int* __restrict__ bsum, int* __restrict__ bscan, int* __restrict__ rowptr)
{
    __shared__ int s[512];
    const int t = threadIdx.x;
    const int v = (t < NBLK) ? bsum[t] : 0;
    s[t] = v;
    __syncthreads();
    #pragma unroll
    for (int off = 1; off < 512; off <<= 1) {
        const int u = (t >= off) ? s[t - off] : 0;
        __syncthreads();
        s[t] += u;
        __syncthreads();
    }
    if (t < NBLK) bscan[t] = s[t] - v;
    if (t == 0) rowptr[N_NODES] = s[NBLK - 1];
}

__global__ __launch_bounds__(256) void rowptr_kernel(
    const int* __restrict__ deg, const int* __restrict__ bscan, int* __restrict__ rowptr)
{
    __shared__ int s[256];
    const int t = threadIdx.x;
    const int i = blockIdx.x * 256 + t;
    const int v = (i < N_NODES) ? deg[i] : 0;
    s[t] = v;
    __syncthreads();
    #pragma unroll
    for (int off = 1; off < 256; off <<= 1) {
        const int u = (t >= off) ? s[t - off] : 0;
        __syncthreads();
        s[t] += u;
        __syncthreads();
    }
    if (i < N_NODES) rowptr[i] = bscan[blockIdx.x] + s[t] - v;
}

// ---------------------------------------------------------------------------
// Pass B: place each block-segment's survivors into CSR slots.
// fill atomics spread over 100K addresses — no contention hotspot.
// ---------------------------------------------------------------------------
__global__ __launch_bounds__(256) void scatterB_kernel(
    const int* __restrict__ qsrc, const int* __restrict__ qdst,
    const float* __restrict__ qw, const int* __restrict__ blockCount,
    const int* __restrict__ rowptr, int* __restrict__ fill,
    int* __restrict__ esrc, float* __restrict__ ew)
{
    const int b = blockIdx.x;
    const int cnt = blockCount[b];
    const int t = threadIdx.x;
    if (t < cnt) {
        const int i = b * 256 + t;
        const int dst = qdst[i];
        const int slot = rowptr[dst] + atomicAdd(fill + dst, 1);
        esrc[slot] = qsrc[i];
        ew[slot] = qw[i];
    }
}

// ---------------------------------------------------------------------------
// Gather layer 1 (one wave per node) + normalize + b1 + ReLU + W2 GEMV -> xp2.
// ---------------------------------------------------------------------------
__global__ __launch_bounds__(256) void gather1_kernel(
    const float* __restrict__ xp1, const float* __restrict__ denom1,
    const int* __restrict__ rowptr, const int* __restrict__ esrc,
    const float* __restrict__ ew,
    const float* __restrict__ b1, const float* __restrict__ W2,
    float* __restrict__ xp2)
{
    const int wid = threadIdx.x >> 6;
    const int lane = threadIdx.x & 63;
    const int i = blockIdx.x * 4 + wid;
    if (i >= N_NODES) return;

    const int begin = rowptr[i];
    const int end   = rowptr[i + 1];
    const float wself = denom1[i];

    const float2 xs = ((const float2*)(xp1 + (size_t)i * HD))[lane];
    float a0 = wself * xs.x, a1 = wself * xs.y;
    float denom = wself;

    int sN = 0; float wN = 0.f;
    if (begin < end) { sN = esrc[begin]; wN = ew[begin]; }
    for (int j = begin; j < end; ++j) {
        const int s = sN; const float w = wN;
        if (j + 1 < end) { sN = esrc[j + 1]; wN = ew[j + 1]; }
        const float2 v = ((const float2*)(xp1 + (size_t)s * HD))[lane];
        a0 += w * v.x;
        a1 += w * v.y;
        denom += w;
    }

    const float inv = 1.f / denom;
    const float o0 = fmaxf(a0 * inv + b1[2 * lane],     0.f);
    const float o1 = fmaxf(a1 * inv + b1[2 * lane + 1], 0.f);

    float part = o0 * W2[2 * lane] + o1 * W2[2 * lane + 1];
    #pragma unroll
    for (int off = 32; off > 0; off >>= 1) part += __shfl_down(part, off, 64);
    if (lane == 0) xp2[i] = part;
}

// ---------------------------------------------------------------------------
// Layer 2 over scalars (one thread per node): reuse the same CSR.
// ---------------------------------------------------------------------------
__global__ __launch_bounds__(256) void final2_kernel(
    const float* __restrict__ xp2, const int* __restrict__ rowptr,
    const int* __restrict__ esrc,
    const float* __restrict__ a_src2, const float* __restrict__ a_dst2,
    const float* __restrict__ b2, float* __restrict__ out)
{
    const int i = blockIdx.x * 256 + threadIdx.x;
    if (i >= N_NODES) return;

    const float as = a_src2[0], ad = a_dst2[0];
    const float xi = xp2[i];
    const float s0 = (as + ad) * xi;
    const float l0 = s0 > 0.f ? s0 : SLOPE * s0;
    const float wself = __expf(l0);

    float denom = wself, num = wself * xi;
    const int end = rowptr[i + 1];
    for (int j = rowptr[i]; j < end; ++j) {
        const float xsv = xp2[esrc[j]];
        const float lg = as * xsv + ad * xi;
        const float ll = lg > 0.f ? lg : SLOPE * lg;
        const float w = __expf(ll);
        denom += w;
        num += w * xsv;
    }
    out[i] = num / denom + b2[0];
}

extern "C" void kernel_launch(void* const* d_in, const int* in_sizes, int n_in,
                              void* d_out, int out_size, void* d_ws, size_t ws_size,
                              hipStream_t stream)
{
    const int* h   = (const int*)d_in[0];
    const int* ei  = (const int*)d_in[1];
    const int* nt  = (const int*)d_in[2];
    const float* emb    = (const float*)d_in[3];
    const float* W1     = (const float*)d_in[4];
    const float* a_src1 = (const float*)d_in[5];
    const float* a_dst1 = (const float*)d_in[6];
    const float* b1     = (const float*)d_in[7];
    const float* W2     = (const float*)d_in[8];
    const float* a_src2 = (const float*)d_in[9];
    const float* a_dst2 = (const float*)d_in[10];
    const float* b2     = (const float*)d_in[11];
    float* out = (float*)d_out;

    char* ws = (char*)d_ws;
    size_t off = 0;
    float* xp1    = (float*)(ws + off); off += (size_t)N_NODES * HD * sizeof(float);
    float* es1    = (float*)(ws + off); off += (size_t)N_NODES * sizeof(float);
    float* ed1    = (float*)(ws + off); off += (size_t)N_NODES * sizeof(float);
    float* denom1 = (float*)(ws + off); off += (size_t)N_NODES * sizeof(float);
    float* xp2    = (float*)(ws + off); off += (size_t)N_NODES * sizeof(float);
    int*   deg    = (int*)(ws + off);   off += (size_t)N_NODES * sizeof(int);
    int*   fill   = (int*)(ws + off);   off += (size_t)N_NODES * sizeof(int);
    int*   rowptr = (int*)(ws + off);   off += ((size_t)N_NODES + 1) * sizeof(int);
    int*   bsum   = (int*)(ws + off);   off += (size_t)NBLK * sizeof(int);
    int*   bscan  = (int*)(ws + off);   off += (size_t)NBLK * sizeof(int);
    int*   bcnt   = (int*)(ws + off);   off += (size_t)EBLK * sizeof(int);
    int*   qsrc   = (int*)(ws + off);   off += (size_t)N_EDGES * sizeof(int);
    int*   qdst   = (int*)(ws + off);   off += (size_t)N_EDGES * sizeof(int);
    float* qw     = (float*)(ws + off); off += (size_t)N_EDGES * sizeof(float);
    int*   esrc   = (int*)(ws + off);   off += (size_t)N_EDGES * sizeof(int);
    float* ew     = (float*)(ws + off); off += (size_t)N_EDGES * sizeof(float);

    zero_kernel<<<NBLK, 256, 0, stream>>>(deg, fill);
    gemm1_kernel<<<(N_NODES + TMR - 1) / TMR, 256, 0, stream>>>(
        h, emb, W1, a_src1, a_dst1, xp1, es1, ed1, denom1);
    edgeA_kernel<<<EBLK, 256, 0, stream>>>(
        ei, nt, es1, ed1, deg, bcnt, qsrc, qdst, qw);
    bsum_kernel<<<NBLK, 256, 0, stream>>>(deg, bsum);
    bscan_kernel<<<1, 512, 0, stream>>>(bsum, bscan, rowptr);
    rowptr_kernel<<<NBLK, 256, 0, stream>>>(deg, bscan, rowptr);
    scatterB_kernel<<<EBLK, 256, 0, stream>>>(
        qsrc, qdst, qw, bcnt, rowptr, fill, esrc, ew);
    gather1_kernel<<<(N_NODES + 3) / 4, 256, 0, stream>>>(
        xp1, denom1, rowptr, esrc, ew, b1, W2, xp2);
    final2_kernel<<<NBLK, 256, 0, stream>>>(
        xp2, rowptr, esrc, a_src2, a_dst2, b2, out);
}

// Round 8
// 222.328 us; speedup vs baseline: 2.3086x; 1.1021x over previous
//
#include <hip/hip_runtime.h>

#define N_NODES 100000
#define N_EDGES 1600000
#define HD 128
#define SLOPE 0.2f
#define NBLK 391  // ceil(N_NODES/256)
#define EBLK (N_EDGES / 256)   // 6250 edge blocks

typedef __attribute__((ext_vector_type(8))) short bf16x8;
typedef __attribute__((ext_vector_type(4))) float f32x4;

__device__ __forceinline__ unsigned short f2bf(float f) {
    union { float f; unsigned u; } v; v.f = f;
    const unsigned u = v.u + 0x7FFFu + ((v.u >> 16) & 1u);   // RNE
    return (unsigned short)(u >> 16);
}
__device__ __forceinline__ unsigned pack2(float lo, float hi) {
    return (unsigned)f2bf(lo) | ((unsigned)f2bf(hi) << 16);
}

// ---------------------------------------------------------------------------
// K1: xp1 = emb[h] @ W1 via bf16 MFMA 16x16x32 (f32 accumulate).
// Block: 128 rows x 128 cols; 4 waves in 2x2; wave: 4x4 C-tiles of 16x16.
// LDS: Xbf[128][128] bf16 + Wt[128][128] bf16 (W1 transposed), 16B chunks
// XOR-swizzled by (row&7) so frag reads are evenly spread across banks.
// Fused: es1/ed1 row-dots (reduce over 16-lane col groups + LDS cross-wave
// combine) and denom1 = exp(leaky(es+ed)).
// ---------------------------------------------------------------------------
__global__ __launch_bounds__(256) void gemm1_kernel(
    const int* __restrict__ h,
    const float* __restrict__ emb,
    const float* __restrict__ W1,
    const float* __restrict__ a_src1,
    const float* __restrict__ a_dst1,
    float* __restrict__ xp1,
    float* __restrict__ es1,
    float* __restrict__ ed1,
    float* __restrict__ denom1)
{
    __shared__ char smem[65536];
    unsigned short* Xbf = (unsigned short*)smem;            // 32 KB
    unsigned short* Wt  = (unsigned short*)(smem + 32768);  // 32 KB

    const int tid  = threadIdx.x;
    const int row0 = blockIdx.x * 128;

    // ---- stage X: thread t -> row r = t>>1, k-half (t&1)*64, cvt f32->bf16 ----
    {
        const int r  = tid >> 1;
        const int kb = (tid & 1) * 64;
        const int grow = (row0 + r < N_NODES) ? (row0 + r) : (N_NODES - 1);
        const float* src = emb + (size_t)h[grow] * HD + kb;
        #pragma unroll
        for (int j = 0; j < 16; ++j) {
            const float4 v = *(const float4*)(src + 4 * j);
            const int k0 = kb + 4 * j;                       // k0 % 4 == 0
            const int p  = (k0 >> 3) ^ (r & 7);              // swizzled chunk
            unsigned* dst = (unsigned*)(Xbf + r * 128 + p * 8 + (k0 & 7));
            dst[0] = pack2(v.x, v.y);
            dst[1] = pack2(v.z, v.w);
        }
    }
    // ---- stage Wt = W1^T: thread t covers k0=4*(t&31), n0=4*(t>>5)+32*it ----
    {
        const int k0 = 4 * (tid & 31);
        #pragma unroll
        for (int it = 0; it < 4; ++it) {
            const int n0 = 4 * (tid >> 5) + 32 * it;
            float4 row[4];
            #pragma unroll
            for (int i = 0; i < 4; ++i)
                row[i] = *(const float4*)(W1 + (size_t)(k0 + i) * HD + n0);
            #pragma unroll
            for (int i2 = 0; i2 < 4; ++i2) {
                const int n = n0 + i2;
                const float e0 = ((const float*)&row[0])[i2];
                const float e1 = ((const float*)&row[1])[i2];
                const float e2 = ((const float*)&row[2])[i2];
                const float e3 = ((const float*)&row[3])[i2];
                const int p = (k0 >> 3) ^ (n & 7);
                unsigned* dst = (unsigned*)(Wt + n * 128 + p * 8 + (k0 & 7));
                dst[0] = pack2(e0, e1);
                dst[1] = pack2(e2, e3);
            }
        }
    }
    __syncthreads();

    const int L  = tid & 63;
    const int w  = tid >> 6;
    const int rh = w >> 1;          // row half (0/1): rows rh*64..+63
    const int ch = w & 1;           // col half
    const int lm = L & 15;          // m/n within 16-tile
    const int lg = L >> 4;          // k-group (8 k's each)

    f32x4 acc[4][4];
    #pragma unroll
    for (int rt = 0; rt < 4; ++rt)
        #pragma unroll
        for (int ct = 0; ct < 4; ++ct) acc[rt][ct] = (f32x4)0.f;

    #pragma unroll
    for (int ks = 0; ks < 4; ++ks) {
        bf16x8 af[4], bfr[4];
        const int c = ks * 4 + lg;                 // 16B chunk index along k
        const int p = (c ^ (lm & 7)) * 8;          // same swizzle for A and B
        #pragma unroll
        for (int rt = 0; rt < 4; ++rt) {
            const int r = rh * 64 + rt * 16 + lm;
            af[rt] = *(const bf16x8*)(Xbf + r * 128 + p);
        }
        #pragma unroll
        for (int ct = 0; ct < 4; ++ct) {
            const int n = ch * 64 + ct * 16 + lm;
            bfr[ct] = *(const bf16x8*)(Wt + n * 128 + p);
        }
        #pragma unroll
        for (int rt = 0; rt < 4; ++rt)
            #pragma unroll
            for (int ct = 0; ct < 4; ++ct)
                acc[rt][ct] = __builtin_amdgcn_mfma_f32_16x16x32_bf16(
                    af[rt], bfr[ct], acc[rt][ct], 0, 0, 0);
    }

    // ---- store xp1 (C/D layout: col = lm, row = lg*4 + reg) ----
    #pragma unroll
    for (int rt = 0; rt < 4; ++rt) {
        #pragma unroll
        for (int reg = 0; reg < 4; ++reg) {
            const int row = row0 + rh * 64 + rt * 16 + lg * 4 + reg;
            if (row < N_NODES) {
                float* dst = xp1 + (size_t)row * HD + ch * 64 + lm;
                #pragma unroll
                for (int ct = 0; ct < 4; ++ct)
                    dst[ct * 16] = acc[rt][ct][reg];
            }
        }
    }

    // ---- attention dots: partial over this wave's 64 cols ----
    float asv[4], adv[4];
    #pragma unroll
    for (int ct = 0; ct < 4; ++ct) {
        asv[ct] = a_src1[ch * 64 + ct * 16 + lm];
        adv[ct] = a_dst1[ch * 64 + ct * 16 + lm];
    }

    __syncthreads();   // all waves done reading Xbf/Wt; safe to reuse smem
    float* pes = (float*)smem;          // [2][128]
    float* ped = pes + 256;             // [2][128]

    #pragma unroll
    for (int rt = 0; rt < 4; ++rt) {
        #pragma unroll
        for (int reg = 0; reg < 4; ++reg) {
            float s = 0.f, d = 0.f;
            #pragma unroll
            for (int ct = 0; ct < 4; ++ct) {
                s += acc[rt][ct][reg] * asv[ct];
                d += acc[rt][ct][reg] * adv[ct];
            }
            #pragma unroll
            for (int m = 1; m < 16; m <<= 1) {
                s += __shfl_xor(s, m, 64);
                d += __shfl_xor(d, m, 64);
            }
            if (lm == 0) {
                const int lrow = rh * 64 + rt * 16 + lg * 4 + reg;
                pes[ch * 128 + lrow] = s;
                ped[ch * 128 + lrow] = d;
            }
        }
    }
    __syncthreads();

    if (tid < 128) {
        const int row = row0 + tid;
        if (row < N_NODES) {
            const float ps = pes[tid] + pes[128 + tid];
            const float pd = ped[tid] + ped[128 + tid];
            const float s = ps + pd;
            const float l = s > 0.f ? s : SLOPE * s;
            es1[row] = ps;
            ed1[row] = pd;
            denom1[row] = __expf(l);
        }
    }
}

__global__ __launch_bounds__(256) void zero_kernel(
    int* __restrict__ deg, int* __restrict__ fill)
{
    const int i = blockIdx.x * 256 + threadIdx.x;
    if (i < N_NODES) { deg[i] = 0; fill[i] = 0; }
}

// ---------------------------------------------------------------------------
// Pass A: gate + deg histogram + block-local compaction (no global tickets).
// ---------------------------------------------------------------------------
__global__ __launch_bounds__(256) void edgeA_kernel(
    const int* __restrict__ ei, const int* __restrict__ nt,
    const float* __restrict__ es1, const float* __restrict__ ed1,
    int* __restrict__ deg, int* __restrict__ blockCount,
    int* __restrict__ qsrc, int* __restrict__ qdst, float* __restrict__ qw)
{
    __shared__ int wcnt[4];
    const int e = blockIdx.x * 256 + threadIdx.x;
    const int wid = threadIdx.x >> 6;
    const int lane = threadIdx.x & 63;

    const int src = ei[e];
    const int dst = ei[N_EDGES + e];
    const bool active = (nt[src] | nt[dst]) == 0;

    const unsigned long long bal = __ballot(active);
    if (lane == 0) wcnt[wid] = (int)__popcll(bal);
    __syncthreads();
    const int c0w = wcnt[0], c1w = wcnt[1], c2w = wcnt[2], c3w = wcnt[3];
    if (threadIdx.x == 0) blockCount[blockIdx.x] = c0w + c1w + c2w + c3w;

    if (active) {
        int base = 0;
        if (wid > 0) base += c0w;
        if (wid > 1) base += c1w;
        if (wid > 2) base += c2w;
        atomicAdd(deg + dst, 1);
        const float logit = es1[src] + ed1[dst];
        const float l = logit > 0.f ? logit : SLOPE * logit;
        const int slot = blockIdx.x * 256 + base +
                         (int)__popcll(bal & ((1ull << lane) - 1ull));
        qsrc[slot] = src;
        qdst[slot] = dst;
        qw[slot] = __expf(l);
    }
}

// ---------------------------------------------------------------------------
// scans: block sums -> block scan -> rowptr
// ---------------------------------------------------------------------------
__global__ __launch_bounds__(256) void bsum_kernel(
    const int* __restrict__ deg, int* __restrict__ bsum)
{
    __shared__ int wsum[4];
    const int i = blockIdx.x * 256 + threadIdx.x;
    int v = (i < N_NODES) ? deg[i] : 0;
    #pragma unroll
    for (int off = 32; off > 0; off >>= 1) v += __shfl_down(v, off, 64);
    if ((threadIdx.x & 63) == 0) wsum[threadIdx.x >> 6] = v;
    __syncthreads();
    if (threadIdx.x == 0) bsum[blockIdx.x] = wsum[0] + wsum[1] + wsum[2] + wsum[3];
}

__global__ __launch_bounds__(512) void bscan_kernel(
    const int* __restrict__ bsum, int* __restrict__ bscan, int* __restrict__ rowptr)
{
    __shared__ int s[512];
    const int t = threadIdx.x;
    const int v = (t < NBLK) ? bsum[t] : 0;
    s[t] = v;
    __syncthreads();
    #pragma unroll
    for (int off = 1; off < 512; off <<= 1) {
        const int u = (t >= off) ? s[t - off] : 0;
        __syncthreads();
        s[t] += u;
        __syncthreads();
    }
    if (t < NBLK) bscan[t] = s[t] - v;
    if (t == 0) rowptr[N_NODES] = s[NBLK - 1];
}

__global__ __launch_bounds__(256) void rowptr_kernel(
    const int* __restrict__ deg, const int* __restrict__ bscan, int* __restrict__ rowptr)
{
    __shared__ int s[256];
    const int t = threadIdx.x;
    const int i = blockIdx.x * 256 + t;
    const int v = (i < N_NODES) ? deg[i] : 0;
    s[t] = v;
    __syncthreads();
    #pragma unroll
    for (int off = 1; off < 256; off <<= 1) {
        const int u = (t >= off) ? s[t - off] : 0;
        __syncthreads();
        s[t] += u;
        __syncthreads();
    }
    if (i < N_NODES) rowptr[i] = bscan[blockIdx.x] + s[t] - v;
}

// ---------------------------------------------------------------------------
// Pass B: place survivors into CSR slots (fill atomics spread over 100K addrs).
// ---------------------------------------------------------------------------
__global__ __launch_bounds__(256) void scatterB_kernel(
    const int* __restrict__ qsrc, const int* __restrict__ qdst,
    const float* __restrict__ qw, const int* __restrict__ blockCount,
    const int* __restrict__ rowptr, int* __restrict__ fill,
    int* __restrict__ esrc, float* __restrict__ ew)
{
    const int b = blockIdx.x;
    const int cnt = blockCount[b];
    const int t = threadIdx.x;
    if (t < cnt) {
        const int i = b * 256 + t;
        const int dst = qdst[i];
        const int slot = rowptr[dst] + atomicAdd(fill + dst, 1);
        esrc[slot] = qsrc[i];
        ew[slot] = qw[i];
    }
}

// ---------------------------------------------------------------------------
// Gather layer 1 (one wave per node) + normalize + b1 + ReLU + W2 GEMV -> xp2.
// ---------------------------------------------------------------------------
__global__ __launch_bounds__(256) void gather1_kernel(
    const float* __restrict__ xp1, const float* __restrict__ denom1,
    const int* __restrict__ rowptr, const int* __restrict__ esrc,
    const float* __restrict__ ew,
    const float* __restrict__ b1, const float* __restrict__ W2,
    float* __restrict__ xp2)
{
    const int wid = threadIdx.x >> 6;
    const int lane = threadIdx.x & 63;
    const int i = blockIdx.x * 4 + wid;
    if (i >= N_NODES) return;

    const int begin = rowptr[i];
    const int end   = rowptr[i + 1];
    const float wself = denom1[i];

    const float2 xs = ((const float2*)(xp1 + (size_t)i * HD))[lane];
    float a0 = wself * xs.x, a1 = wself * xs.y;
    float denom = wself;

    int sN = 0; float wN = 0.f;
    if (begin < end) { sN = esrc[begin]; wN = ew[begin]; }
    for (int j = begin; j < end; ++j) {
        const int s = sN; const float w = wN;
        if (j + 1 < end) { sN = esrc[j + 1]; wN = ew[j + 1]; }
        const float2 v = ((const float2*)(xp1 + (size_t)s * HD))[lane];
        a0 += w * v.x;
        a1 += w * v.y;
        denom += w;
    }

    const float inv = 1.f / denom;
    const float o0 = fmaxf(a0 * inv + b1[2 * lane],     0.f);
    const float o1 = fmaxf(a1 * inv + b1[2 * lane + 1], 0.f);

    float part = o0 * W2[2 * lane] + o1 * W2[2 * lane + 1];
    #pragma unroll
    for (int off = 32; off > 0; off >>= 1) part += __shfl_down(part, off, 64);
    if (lane == 0) xp2[i] = part;
}

// ---------------------------------------------------------------------------
// Layer 2 over scalars (one thread per node): reuse the same CSR.
// ---------------------------------------------------------------------------
__global__ __launch_bounds__(256) void final2_kernel(
    const float* __restrict__ xp2, const int* __restrict__ rowptr,
    const int* __restrict__ esrc,
    const float* __restrict__ a_src2, const float* __restrict__ a_dst2,
    const float* __restrict__ b2, float* __restrict__ out)
{
    const int i = blockIdx.x * 256 + threadIdx.x;
    if (i >= N_NODES) return;

    const float as = a_src2[0], ad = a_dst2[0];
    const float xi = xp2[i];
    const float s0 = (as + ad) * xi;
    const float l0 = s0 > 0.f ? s0 : SLOPE * s0;
    const float wself = __expf(l0);

    float denom = wself, num = wself * xi;
    const int end = rowptr[i + 1];
    for (int j = rowptr[i]; j < end; ++j) {
        const float xsv = xp2[esrc[j]];
        const float lg = as * xsv + ad * xi;
        const float ll = lg > 0.f ? lg : SLOPE * lg;
        const float w = __expf(ll);
        denom += w;
        num += w * xsv;
    }
    out[i] = num / denom + b2[0];
}

extern "C" void kernel_launch(void* const* d_in, const int* in_sizes, int n_in,
                              void* d_out, int out_size, void* d_ws, size_t ws_size,
                              hipStream_t stream)
{
    const int* h   = (const int*)d_in[0];
    const int* ei  = (const int*)d_in[1];
    const int* nt  = (const int*)d_in[2];
    const float* emb    = (const float*)d_in[3];
    const float* W1     = (const float*)d_in[4];
    const float* a_src1 = (const float*)d_in[5];
    const float* a_dst1 = (const float*)d_in[6];
    const float* b1     = (const float*)d_in[7];
    const float* W2     = (const float*)d_in[8];
    const float* a_src2 = (const float*)d_in[9];
    const float* a_dst2 = (const float*)d_in[10];
    const float* b2     = (const float*)d_in[11];
    float* out = (float*)d_out;

    char* ws = (char*)d_ws;
    size_t off = 0;
    float* xp1    = (float*)(ws + off); off += (size_t)N_NODES * HD * sizeof(float);
    float* es1    = (float*)(ws + off); off += (size_t)N_NODES * sizeof(float);
    float* ed1    = (float*)(ws + off); off += (size_t)N_NODES * sizeof(float);
    float* denom1 = (float*)(ws + off); off += (size_t)N_NODES * sizeof(float);
    float* xp2    = (float*)(ws + off); off += (size_t)N_NODES * sizeof(float);
    int*   deg    = (int*)(ws + off);   off += (size_t)N_NODES * sizeof(int);
    int*   fill   = (int*)(ws + off);   off += (size_t)N_NODES * sizeof(int);
    int*   rowptr = (int*)(ws + off);   off += ((size_t)N_NODES + 1) * sizeof(int);
    int*   bsum   = (int*)(ws + off);   off += (size_t)NBLK * sizeof(int);
    int*   bscan  = (int*)(ws + off);   off += (size_t)NBLK * sizeof(int);
    int*   bcnt   = (int*)(ws + off);   off += (size_t)EBLK * sizeof(int);
    int*   qsrc   = (int*)(ws + off);   off += (size_t)N_EDGES * sizeof(int);
    int*   qdst   = (int*)(ws + off);   off += (size_t)N_EDGES * sizeof(int);
    float* qw     = (float*)(ws + off); off += (size_t)N_EDGES * sizeof(float);
    int*   esrc   = (int*)(ws + off);   off += (size_t)N_EDGES * sizeof(int);
    float* ew     = (float*)(ws + off); off += (size_t)N_EDGES * sizeof(float);

    zero_kernel<<<NBLK, 256, 0, stream>>>(deg, fill);
    gemm1_kernel<<<(N_NODES + 127) / 128, 256, 0, stream>>>(
        h, emb, W1, a_src1, a_dst1, xp1, es1, ed1, denom1);
    edgeA_kernel<<<EBLK, 256, 0, stream>>>(
        ei, nt, es1, ed1, deg, bcnt, qsrc, qdst, qw);
    bsum_kernel<<<NBLK, 256, 0, stream>>>(deg, bsum);
    bscan_kernel<<<1, 512, 0, stream>>>(bsum, bscan, rowptr);
    rowptr_kernel<<<NBLK, 256, 0, stream>>>(deg, bscan, rowptr);
    scatterB_kernel<<<EBLK, 256, 0, stream>>>(
        qsrc, qdst, qw, bcnt, rowptr, fill, esrc, ew);
    gather1_kernel<<<(N_NODES + 3) / 4, 256, 0, stream>>>(
        xp1, denom1, rowptr, esrc, ew, b1, W2, xp2);
    final2_kernel<<<NBLK, 256, 0, stream>>>(
        xp2, rowptr, esrc, a_src2, a_dst2, b2, out);
}

// Round 9
// 220.340 us; speedup vs baseline: 2.3294x; 1.0090x over previous
//
#include <hip/hip_runtime.h>

#define N_NODES 100000
#define N_EDGES 1600000
#define HD 128
#define SLOPE 0.2f
#define NBLK 391  // ceil(N_NODES/256)
#define EBLK (N_EDGES / 256)   // 6250 edge blocks

typedef __attribute__((ext_vector_type(8))) short bf16x8;
typedef __attribute__((ext_vector_type(4))) float f32x4;

__device__ __forceinline__ unsigned short f2bf(float f) {
    union { float f; unsigned u; } v; v.f = f;
    const unsigned u = v.u + 0x7FFFu + ((v.u >> 16) & 1u);   // RNE
    return (unsigned short)(u >> 16);
}
__device__ __forceinline__ unsigned pack2(float lo, float hi) {
    return (unsigned)f2bf(lo) | ((unsigned)f2bf(hi) << 16);
}

// ---------------------------------------------------------------------------
// P0: W1bfT[n][k] = bf16(W1[k][n]) — one-time transpose+convert (32 KB, L2-hot).
// ---------------------------------------------------------------------------
__global__ __launch_bounds__(128) void prepw_kernel(
    const float* __restrict__ W1, unsigned short* __restrict__ W1bfT)
{
    const int n = blockIdx.x;        // 0..127
    const int k = threadIdx.x;       // 0..127
    W1bfT[n * HD + k] = f2bf(W1[k * HD + n]);
}

// ---------------------------------------------------------------------------
// K0: zero deg/fill + build node-active bitmask (12.5 KB -> L1-resident).
// ---------------------------------------------------------------------------
__global__ __launch_bounds__(256) void zero_kernel(
    const int* __restrict__ nt,
    int* __restrict__ deg, int* __restrict__ fill, unsigned* __restrict__ umask)
{
    const int i = blockIdx.x * 256 + threadIdx.x;
    bool act = false;
    if (i < N_NODES) { deg[i] = 0; fill[i] = 0; act = (nt[i] == 0); }
    const unsigned long long bal = __ballot(act);
    const int lane = threadIdx.x & 63;
    if (lane == 0)       umask[i >> 5] = (unsigned)bal;
    else if (lane == 32) umask[i >> 5] = (unsigned)(bal >> 32);
}

// ---------------------------------------------------------------------------
// K1: xp1 = emb[h] @ W1 via bf16 MFMA 16x16x32 — ZERO-LDS variant.
// Each (row,kchunk) A-frag / (col,kchunk) B-frag is owned by exactly one
// lane, so frags load straight from global: B from precomputed bf16 W1^T
// (16B loads), A from emb f32 + in-register cvt. No tiles, no barriers in
// the K-loop. LDS only for the 2KB epilogue cross-wave combine.
// Block: 128 rows x 128 cols, 4 waves 2x2, wave: 4x4 tiles of 16x16.
// ---------------------------------------------------------------------------
__global__ __launch_bounds__(256) void gemm1_kernel(
    const int* __restrict__ h,
    const float* __restrict__ emb,
    const unsigned short* __restrict__ W1bfT,
    const float* __restrict__ a_src1,
    const float* __restrict__ a_dst1,
    float* __restrict__ xp1,
    float* __restrict__ es1,
    float* __restrict__ ed1,
    float* __restrict__ denom1)
{
    __shared__ float pes[256];
    __shared__ float ped[256];

    const int tid  = threadIdx.x;
    const int row0 = blockIdx.x * 128;
    const int L  = tid & 63;
    const int w  = tid >> 6;
    const int rh = w >> 1;          // row half
    const int ch = w & 1;           // col half
    const int lm = L & 15;
    const int lg = L >> 4;

    const float* xrow[4];
    #pragma unroll
    for (int rt = 0; rt < 4; ++rt) {
        const int row = row0 + rh * 64 + rt * 16 + lm;
        const int g = (row < N_NODES) ? row : (N_NODES - 1);
        xrow[rt] = emb + (size_t)h[g] * HD;
    }

    f32x4 acc[4][4];
    #pragma unroll
    for (int rt = 0; rt < 4; ++rt)
        #pragma unroll
        for (int ct = 0; ct < 4; ++ct) acc[rt][ct] = (f32x4)0.f;

    #pragma unroll
    for (int ks = 0; ks < 4; ++ks) {
        const int k0 = ks * 32 + lg * 8;
        bf16x8 af[4], bfr[4];
        #pragma unroll
        for (int rt = 0; rt < 4; ++rt) {
            const float4 u = *(const float4*)(xrow[rt] + k0);
            const float4 v = *(const float4*)(xrow[rt] + k0 + 4);
            union { bf16x8 b; unsigned x[4]; } t;
            t.x[0] = pack2(u.x, u.y);
            t.x[1] = pack2(u.z, u.w);
            t.x[2] = pack2(v.x, v.y);
            t.x[3] = pack2(v.z, v.w);
            af[rt] = t.b;
        }
        #pragma unroll
        for (int ct = 0; ct < 4; ++ct) {
            const int n = ch * 64 + ct * 16 + lm;
            bfr[ct] = *(const bf16x8*)(W1bfT + n * HD + k0);
        }
        #pragma unroll
        for (int rt = 0; rt < 4; ++rt)
            #pragma unroll
            for (int ct = 0; ct < 4; ++ct)
                acc[rt][ct] = __builtin_amdgcn_mfma_f32_16x16x32_bf16(
                    af[rt], bfr[ct], acc[rt][ct], 0, 0, 0);
    }

    // ---- store xp1 (C/D layout: col = lm, row = lg*4 + reg) ----
    #pragma unroll
    for (int rt = 0; rt < 4; ++rt) {
        #pragma unroll
        for (int reg = 0; reg < 4; ++reg) {
            const int row = row0 + rh * 64 + rt * 16 + lg * 4 + reg;
            if (row < N_NODES) {
                float* dst = xp1 + (size_t)row * HD + ch * 64 + lm;
                #pragma unroll
                for (int ct = 0; ct < 4; ++ct)
                    dst[ct * 16] = acc[rt][ct][reg];
            }
        }
    }

    // ---- fused attention dots ----
    float asv[4], adv[4];
    #pragma unroll
    for (int ct = 0; ct < 4; ++ct) {
        asv[ct] = a_src1[ch * 64 + ct * 16 + lm];
        adv[ct] = a_dst1[ch * 64 + ct * 16 + lm];
    }

    #pragma unroll
    for (int rt = 0; rt < 4; ++rt) {
        #pragma unroll
        for (int reg = 0; reg < 4; ++reg) {
            float s = 0.f, d = 0.f;
            #pragma unroll
            for (int ct = 0; ct < 4; ++ct) {
                s += acc[rt][ct][reg] * asv[ct];
                d += acc[rt][ct][reg] * adv[ct];
            }
            #pragma unroll
            for (int m = 1; m < 16; m <<= 1) {
                s += __shfl_xor(s, m, 64);
                d += __shfl_xor(d, m, 64);
            }
            if (lm == 0) {
                const int lrow = rh * 64 + rt * 16 + lg * 4 + reg;
                pes[ch * 128 + lrow] = s;
                ped[ch * 128 + lrow] = d;
            }
        }
    }
    __syncthreads();

    if (tid < 128) {
        const int row = row0 + tid;
        if (row < N_NODES) {
            const float ps = pes[tid] + pes[128 + tid];
            const float pd = ped[tid] + ped[128 + tid];
            const float s = ps + pd;
            const float l = s > 0.f ? s : SLOPE * s;
            es1[row] = ps;
            ed1[row] = pd;
            denom1[row] = __expf(l);
        }
    }
}

// ---------------------------------------------------------------------------
// Pass A: gate via L1-resident bitmask + deg histogram + block-local compaction.
// ---------------------------------------------------------------------------
__global__ __launch_bounds__(256) void edgeA_kernel(
    const int* __restrict__ ei, const unsigned* __restrict__ umask,
    const float* __restrict__ es1, const float* __restrict__ ed1,
    int* __restrict__ deg, int* __restrict__ blockCount,
    int* __restrict__ qsrc, int* __restrict__ qdst, float* __restrict__ qw)
{
    __shared__ int wcnt[4];
    const int e = blockIdx.x * 256 + threadIdx.x;
    const int wid = threadIdx.x >> 6;
    const int lane = threadIdx.x & 63;

    const int src = ei[e];
    const int dst = ei[N_EDGES + e];
    const bool active =
        (((umask[src >> 5] >> (src & 31)) & (umask[dst >> 5] >> (dst & 31))) & 1u) != 0u;

    const unsigned long long bal = __ballot(active);
    if (lane == 0) wcnt[wid] = (int)__popcll(bal);
    __syncthreads();
    const int c0w = wcnt[0], c1w = wcnt[1], c2w = wcnt[2], c3w = wcnt[3];
    if (threadIdx.x == 0) blockCount[blockIdx.x] = c0w + c1w + c2w + c3w;

    if (active) {
        int base = 0;
        if (wid > 0) base += c0w;
        if (wid > 1) base += c1w;
        if (wid > 2) base += c2w;
        atomicAdd(deg + dst, 1);
        const float logit = es1[src] + ed1[dst];
        const float l = logit > 0.f ? logit : SLOPE * logit;
        const int slot = blockIdx.x * 256 + base +
                         (int)__popcll(bal & ((1ull << lane) - 1ull));
        qsrc[slot] = src;
        qdst[slot] = dst;
        qw[slot] = __expf(l);
    }
}

// ---------------------------------------------------------------------------
// scans: block sums -> block scan -> rowptr
// ---------------------------------------------------------------------------
__global__ __launch_bounds__(256) void bsum_kernel(
    const int* __restrict__ deg, int* __restrict__ bsum)
{
    __shared__ int wsum[4];
    const int i = blockIdx.x * 256 + threadIdx.x;
    int v = (i < N_NODES) ? deg[i] : 0;
    #pragma unroll
    for (int off = 32; off > 0; off >>= 1) v += __shfl_down(v, off, 64);
    if ((threadIdx.x & 63) == 0) wsum[threadIdx.x >> 6] = v;
    __syncthreads();
    if (threadIdx.x == 0) bsum[blockIdx.x] = wsum[0] + wsum[1] + wsum[2] + wsum[3];
}

__global__ __launch_bounds__(512) void bscan_kernel(
    const int* __restrict__ bsum, int* __restrict__ bscan, int* __restrict__ rowptr)
{
    __shared__ int s[512];
    const int t = threadIdx.x;
    const int v = (t < NBLK) ? bsum[t] : 0;
    s[t] = v;
    __syncthreads();
    #pragma unroll
    for (int off = 1; off < 512; off <<= 1) {
        const int u = (t >= off) ? s[t - off] : 0;
        __syncthreads();
        s[t] += u;
        __syncthreads();
    }
    if (t < NBLK) bscan[t] = s[t] - v;
    if (t == 0) rowptr[N_NODES] = s[NBLK - 1];
}

__global__ __launch_bounds__(256) void rowptr_kernel(
    const int* __restrict__ deg, const int* __restrict__ bscan, int* __restrict__ rowptr)
{
    __shared__ int s[256];
    const int t = threadIdx.x;
    const int i = blockIdx.x * 256 + t;
    const int v = (i < N_NODES) ? deg[i] : 0;
    s[t] = v;
    __syncthreads();
    #pragma unroll
    for (int off = 1; off < 256; off <<= 1) {
        const int u = (t >= off) ? s[t - off] : 0;
        __syncthreads();
        s[t] += u;
        __syncthreads();
    }
    if (i < N_NODES) rowptr[i] = bscan[blockIdx.x] + s[t] - v;
}

// ---------------------------------------------------------------------------
// Pass B: place survivors into CSR slots (fill atomics spread over 100K addrs).
// ---------------------------------------------------------------------------
__global__ __launch_bounds__(256) void scatterB_kernel(
    const int* __restrict__ qsrc, const int* __restrict__ qdst,
    const float* __restrict__ qw, const int* __restrict__ blockCount,
    const int* __restrict__ rowptr, int* __restrict__ fill,
    int* __restrict__ esrc, float* __restrict__ ew)
{
    const int b = blockIdx.x;
    const int cnt = blockCount[b];
    const int t = threadIdx.x;
    if (t < cnt) {
        const int i = b * 256 + t;
        const int dst = qdst[i];
        const int slot = rowptr[dst] + atomicAdd(fill + dst, 1);
        esrc[slot] = qsrc[i];
        ew[slot] = qw[i];
    }
}

// ---------------------------------------------------------------------------
// Gather layer 1 (one wave per node) + normalize + b1 + ReLU + W2 GEMV -> xp2.
// ---------------------------------------------------------------------------
__global__ __launch_bounds__(256) void gather1_kernel(
    const float* __restrict__ xp1, const float* __restrict__ denom1,
    const int* __restrict__ rowptr, const int* __restrict__ esrc,
    const float* __restrict__ ew,
    const float* __restrict__ b1, const float* __restrict__ W2,
    float* __restrict__ xp2)
{
    const int wid = threadIdx.x >> 6;
    const int lane = threadIdx.x & 63;
    const int i = blockIdx.x * 4 + wid;
    if (i >= N_NODES) return;

    const int begin = rowptr[i];
    const int end   = rowptr[i + 1];
    const float wself = denom1[i];

    const float2 xs = ((const float2*)(xp1 + (size_t)i * HD))[lane];
    float a0 = wself * xs.x, a1 = wself * xs.y;
    float denom = wself;

    int sN = 0; float wN = 0.f;
    if (begin < end) { sN = esrc[begin]; wN = ew[begin]; }
    for (int j = begin; j < end; ++j) {
        const int s = sN; const float w = wN;
        if (j + 1 < end) { sN = esrc[j + 1]; wN = ew[j + 1]; }
        const float2 v = ((const float2*)(xp1 + (size_t)s * HD))[lane];
        a0 += w * v.x;
        a1 += w * v.y;
        denom += w;
    }

    const float inv = 1.f / denom;
    const float o0 = fmaxf(a0 * inv + b1[2 * lane],     0.f);
    const float o1 = fmaxf(a1 * inv + b1[2 * lane + 1], 0.f);

    float part = o0 * W2[2 * lane] + o1 * W2[2 * lane + 1];
    #pragma unroll
    for (int off = 32; off > 0; off >>= 1) part += __shfl_down(part, off, 64);
    if (lane == 0) xp2[i] = part;
}

// ---------------------------------------------------------------------------
// Layer 2 over scalars (one thread per node): reuse the same CSR.
// ---------------------------------------------------------------------------
__global__ __launch_bounds__(256) void final2_kernel(
    const float* __restrict__ xp2, const int* __restrict__ rowptr,
    const int* __restrict__ esrc,
    const float* __restrict__ a_src2, const float* __restrict__ a_dst2,
    const float* __restrict__ b2, float* __restrict__ out)
{
    const int i = blockIdx.x * 256 + threadIdx.x;
    if (i >= N_NODES) return;

    const float as = a_src2[0], ad = a_dst2[0];
    const float xi = xp2[i];
    const float s0 = (as + ad) * xi;
    const float l0 = s0 > 0.f ? s0 : SLOPE * s0;
    const float wself = __expf(l0);

    float denom = wself, num = wself * xi;
    const int end = rowptr[i + 1];
    for (int j = rowptr[i]; j < end; ++j) {
        const float xsv = xp2[esrc[j]];
        const float lg = as * xsv + ad * xi;
        const float ll = lg > 0.f ? lg : SLOPE * lg;
        const float w = __expf(ll);
        denom += w;
        num += w * xsv;
    }
    out[i] = num / denom + b2[0];
}

extern "C" void kernel_launch(void* const* d_in, const int* in_sizes, int n_in,
                              void* d_out, int out_size, void* d_ws, size_t ws_size,
                              hipStream_t stream)
{
    const int* h   = (const int*)d_in[0];
    const int* ei  = (const int*)d_in[1];
    const int* nt  = (const int*)d_in[2];
    const float* emb    = (const float*)d_in[3];
    const float* W1     = (const float*)d_in[4];
    const float* a_src1 = (const float*)d_in[5];
    const float* a_dst1 = (const float*)d_in[6];
    const float* b1     = (const float*)d_in[7];
    const float* W2     = (const float*)d_in[8];
    const float* a_src2 = (const float*)d_in[9];
    const float* a_dst2 = (const float*)d_in[10];
    const float* b2     = (const float*)d_in[11];
    float* out = (float*)d_out;

    char* ws = (char*)d_ws;
    size_t off = 0;
    float* xp1    = (float*)(ws + off); off += (size_t)N_NODES * HD * sizeof(float);
    float* es1    = (float*)(ws + off); off += (size_t)N_NODES * sizeof(float);
    float* ed1    = (float*)(ws + off); off += (size_t)N_NODES * sizeof(float);
    float* denom1 = (float*)(ws + off); off += (size_t)N_NODES * sizeof(float);
    float* xp2    = (float*)(ws + off); off += (size_t)N_NODES * sizeof(float);
    int*   deg    = (int*)(ws + off);   off += (size_t)N_NODES * sizeof(int);
    int*   fill   = (int*)(ws + off);   off += (size_t)N_NODES * sizeof(int);
    int*   rowptr = (int*)(ws + off);   off += ((size_t)N_NODES + 1) * sizeof(int);
    int*   bsum   = (int*)(ws + off);   off += (size_t)NBLK * sizeof(int);
    int*   bscan  = (int*)(ws + off);   off += (size_t)NBLK * sizeof(int);
    int*   bcnt   = (int*)(ws + off);   off += (size_t)EBLK * sizeof(int);
    unsigned* umask = (unsigned*)(ws + off); off += 3200 * sizeof(unsigned);
    unsigned short* W1bfT = (unsigned short*)(ws + off); off += (size_t)HD * HD * sizeof(unsigned short);
    off = (off + 255) & ~(size_t)255;
    int*   qsrc   = (int*)(ws + off);   off += (size_t)N_EDGES * sizeof(int);
    int*   qdst   = (int*)(ws + off);   off += (size_t)N_EDGES * sizeof(int);
    float* qw     = (float*)(ws + off); off += (size_t)N_EDGES * sizeof(float);
    int*   esrc   = (int*)(ws + off);   off += (size_t)N_EDGES * sizeof(int);
    float* ew     = (float*)(ws + off); off += (size_t)N_EDGES * sizeof(float);

    prepw_kernel<<<HD, HD, 0, stream>>>(W1, W1bfT);
    zero_kernel<<<NBLK, 256, 0, stream>>>(nt, deg, fill, umask);
    gemm1_kernel<<<(N_NODES + 127) / 128, 256, 0, stream>>>(
        h, emb, W1bfT, a_src1, a_dst1, xp1, es1, ed1, denom1);
    edgeA_kernel<<<EBLK, 256, 0, stream>>>(
        ei, umask, es1, ed1, deg, bcnt, qsrc, qdst, qw);
    bsum_kernel<<<NBLK, 256, 0, stream>>>(deg, bsum);
    bscan_kernel<<<1, 512, 0, stream>>>(bsum, bscan, rowptr);
    rowptr_kernel<<<NBLK, 256, 0, stream>>>(deg, bscan, rowptr);
    scatterB_kernel<<<EBLK, 256, 0, stream>>>(
        qsrc, qdst, qw, bcnt, rowptr, fill, esrc, ew);
    gather1_kernel<<<(N_NODES + 3) / 4, 256, 0, stream>>>(
        xp1, denom1, rowptr, esrc, ew, b1, W2, xp2);
    final2_kernel<<<NBLK, 256, 0, stream>>>(
        xp2, rowptr, esrc, a_src2, a_dst2, b2, out);
}

// Round 10
// 219.621 us; speedup vs baseline: 2.3370x; 1.0033x over previous
//
#include <hip/hip_runtime.h>

#define N_NODES 100000
#define N_EDGES 1600000
#define HD 128
#define SLOPE 0.2f
#define NBLK 391  // ceil(N_NODES/256)
#define EBLK (N_EDGES / 256)   // 6250 edge blocks

typedef __attribute__((ext_vector_type(8))) short bf16x8;
typedef __attribute__((ext_vector_type(4))) float f32x4;

__device__ __forceinline__ unsigned short f2bf(float f) {
    union { float f; unsigned u; } v; v.f = f;
    const unsigned u = v.u + 0x7FFFu + ((v.u >> 16) & 1u);   // RNE
    return (unsigned short)(u >> 16);
}
__device__ __forceinline__ unsigned pack2(float lo, float hi) {
    return (unsigned)f2bf(lo) | ((unsigned)f2bf(hi) << 16);
}
__device__ __forceinline__ float bf2f(unsigned u16) {
    union { unsigned u; float f; } v; v.u = u16 << 16; return v.f;
}

// ---------------------------------------------------------------------------
// P0: W1bfT[n][k] = bf16(W1[k][n]) — one-time transpose+convert (32 KB, L2-hot).
// ---------------------------------------------------------------------------
__global__ __launch_bounds__(128) void prepw_kernel(
    const float* __restrict__ W1, unsigned short* __restrict__ W1bfT)
{
    const int n = blockIdx.x;
    const int k = threadIdx.x;
    W1bfT[n * HD + k] = f2bf(W1[k * HD + n]);
}

// ---------------------------------------------------------------------------
// K0: zero deg/fill + build node-active bitmask (12.5 KB -> L1-resident).
// ---------------------------------------------------------------------------
__global__ __launch_bounds__(256) void zero_kernel(
    const int* __restrict__ nt,
    int* __restrict__ deg, int* __restrict__ fill, unsigned* __restrict__ umask)
{
    const int i = blockIdx.x * 256 + threadIdx.x;
    bool act = false;
    if (i < N_NODES) { deg[i] = 0; fill[i] = 0; act = (nt[i] == 0); }
    const unsigned long long bal = __ballot(act);
    const int lane = threadIdx.x & 63;
    if (lane == 0)       umask[i >> 5] = (unsigned)bal;
    else if (lane == 32) umask[i >> 5] = (unsigned)(bal >> 32);
}

// ---------------------------------------------------------------------------
// K1: xp1 = emb[h] @ W1 via bf16 MFMA 16x16x32 — zero-LDS, high-parallelism.
// Block = 64 rows; each wave owns 16 rows x ALL 128 cols (8 accs):
//  - no A-fetch duplication (r9's 2x2 wave grid read A and B twice),
//  - es/ed reduce fully in-wave (no LDS, no barrier),
//  - 1563 blocks * 4 waves = 6.1 waves/SIMD of memory parallelism (vs 3).
// xp1 stored as bf16 (halves this write AND gather1's read stream).
// ---------------------------------------------------------------------------
__global__ __launch_bounds__(256) void gemm1_kernel(
    const int* __restrict__ h,
    const float* __restrict__ emb,
    const unsigned short* __restrict__ W1bfT,
    const float* __restrict__ a_src1,
    const float* __restrict__ a_dst1,
    unsigned short* __restrict__ xp1,
    float* __restrict__ es1,
    float* __restrict__ ed1,
    float* __restrict__ denom1)
{
    const int tid = threadIdx.x;
    const int w   = tid >> 6;
    const int L   = tid & 63;
    const int lm  = L & 15;
    const int lg  = L >> 4;
    const int wrow0 = blockIdx.x * 64 + w * 16;

    // A: lane lm owns node row wrow0+lm
    const int arow = wrow0 + lm;
    const int g = (arow < N_NODES) ? arow : (N_NODES - 1);
    const float* xrow = emb + (size_t)h[g] * HD;

    f32x4 acc[8];
    #pragma unroll
    for (int ct = 0; ct < 8; ++ct) acc[ct] = (f32x4)0.f;

    #pragma unroll
    for (int ks = 0; ks < 4; ++ks) {
        const int k0 = ks * 32 + lg * 8;
        const float4 u = *(const float4*)(xrow + k0);
        const float4 v = *(const float4*)(xrow + k0 + 4);
        union { bf16x8 b; unsigned x[4]; } t;
        t.x[0] = pack2(u.x, u.y);
        t.x[1] = pack2(u.z, u.w);
        t.x[2] = pack2(v.x, v.y);
        t.x[3] = pack2(v.z, v.w);
        const bf16x8 af = t.b;

        bf16x8 bfr[8];
        #pragma unroll
        for (int ct = 0; ct < 8; ++ct)
            bfr[ct] = *(const bf16x8*)(W1bfT + (ct * 16 + lm) * HD + k0);

        #pragma unroll
        for (int ct = 0; ct < 8; ++ct)
            acc[ct] = __builtin_amdgcn_mfma_f32_16x16x32_bf16(af, bfr[ct], acc[ct], 0, 0, 0);
    }

    // ---- attention dots + store (C/D: col = lm, row-in-tile = lg*4+reg) ----
    float asv[8], adv[8];
    #pragma unroll
    for (int ct = 0; ct < 8; ++ct) {
        asv[ct] = a_src1[ct * 16 + lm];
        adv[ct] = a_dst1[ct * 16 + lm];
    }

    #pragma unroll
    for (int reg = 0; reg < 4; ++reg) {
        const int row = wrow0 + lg * 4 + reg;
        float s = 0.f, d = 0.f;
        #pragma unroll
        for (int ct = 0; ct < 8; ++ct) {
            s += acc[ct][reg] * asv[ct];
            d += acc[ct][reg] * adv[ct];
        }
        #pragma unroll
        for (int m = 1; m < 16; m <<= 1) {   // reduce over the 16 lm lanes
            s += __shfl_xor(s, m, 64);
            d += __shfl_xor(d, m, 64);
        }
        if (row < N_NODES) {
            unsigned short* dst = xp1 + (size_t)row * HD;
            #pragma unroll
            for (int ct = 0; ct < 8; ++ct)
                dst[ct * 16 + lm] = f2bf(acc[ct][reg]);
            if (lm == 0) {
                const float sum = s + d;
                const float l = sum > 0.f ? sum : SLOPE * sum;
                es1[row] = s;
                ed1[row] = d;
                denom1[row] = __expf(l);
            }
        }
    }
}

// ---------------------------------------------------------------------------
// Pass A: gate via L1-resident bitmask + deg histogram + block-local compaction.
// ---------------------------------------------------------------------------
__global__ __launch_bounds__(256) void edgeA_kernel(
    const int* __restrict__ ei, const unsigned* __restrict__ umask,
    const float* __restrict__ es1, const float* __restrict__ ed1,
    int* __restrict__ deg, int* __restrict__ blockCount,
    int* __restrict__ qsrc, int* __restrict__ qdst, float* __restrict__ qw)
{
    __shared__ int wcnt[4];
    const int e = blockIdx.x * 256 + threadIdx.x;
    const int wid = threadIdx.x >> 6;
    const int lane = threadIdx.x & 63;

    const int src = ei[e];
    const int dst = ei[N_EDGES + e];
    const bool active =
        (((umask[src >> 5] >> (src & 31)) & (umask[dst >> 5] >> (dst & 31))) & 1u) != 0u;

    const unsigned long long bal = __ballot(active);
    if (lane == 0) wcnt[wid] = (int)__popcll(bal);
    __syncthreads();
    const int c0w = wcnt[0], c1w = wcnt[1], c2w = wcnt[2], c3w = wcnt[3];
    if (threadIdx.x == 0) blockCount[blockIdx.x] = c0w + c1w + c2w + c3w;

    if (active) {
        int base = 0;
        if (wid > 0) base += c0w;
        if (wid > 1) base += c1w;
        if (wid > 2) base += c2w;
        atomicAdd(deg + dst, 1);
        const float logit = es1[src] + ed1[dst];
        const float l = logit > 0.f ? logit : SLOPE * logit;
        const int slot = blockIdx.x * 256 + base +
                         (int)__popcll(bal & ((1ull << lane) - 1ull));
        qsrc[slot] = src;
        qdst[slot] = dst;
        qw[slot] = __expf(l);
    }
}

// ---------------------------------------------------------------------------
// scans: block sums -> block scan -> rowptr
// ---------------------------------------------------------------------------
__global__ __launch_bounds__(256) void bsum_kernel(
    const int* __restrict__ deg, int* __restrict__ bsum)
{
    __shared__ int wsum[4];
    const int i = blockIdx.x * 256 + threadIdx.x;
    int v = (i < N_NODES) ? deg[i] : 0;
    #pragma unroll
    for (int off = 32; off > 0; off >>= 1) v += __shfl_down(v, off, 64);
    if ((threadIdx.x & 63) == 0) wsum[threadIdx.x >> 6] = v;
    __syncthreads();
    if (threadIdx.x == 0) bsum[blockIdx.x] = wsum[0] + wsum[1] + wsum[2] + wsum[3];
}

__global__ __launch_bounds__(512) void bscan_kernel(
    const int* __restrict__ bsum, int* __restrict__ bscan, int* __restrict__ rowptr)
{
    __shared__ int s[512];
    const int t = threadIdx.x;
    const int v = (t < NBLK) ? bsum[t] : 0;
    s[t] = v;
    __syncthreads();
    #pragma unroll
    for (int off = 1; off < 512; off <<= 1) {
        const int u = (t >= off) ? s[t - off] : 0;
        __syncthreads();
        s[t] += u;
        __syncthreads();
    }
    if (t < NBLK) bscan[t] = s[t] - v;
    if (t == 0) rowptr[N_NODES] = s[NBLK - 1];
}

__global__ __launch_bounds__(256) void rowptr_kernel(
    const int* __restrict__ deg, const int* __restrict__ bscan, int* __restrict__ rowptr)
{
    __shared__ int s[256];
    const int t = threadIdx.x;
    const int i = blockIdx.x * 256 + t;
    const int v = (i < N_NODES) ? deg[i] : 0;
    s[t] = v;
    __syncthreads();
    #pragma unroll
    for (int off = 1; off < 256; off <<= 1) {
        const int u = (t >= off) ? s[t - off] : 0;
        __syncthreads();
        s[t] += u;
        __syncthreads();
    }
    if (i < N_NODES) rowptr[i] = bscan[blockIdx.x] + s[t] - v;
}

// ---------------------------------------------------------------------------
// Pass B: place survivors into CSR slots (fill atomics spread over 100K addrs).
// ---------------------------------------------------------------------------
__global__ __launch_bounds__(256) void scatterB_kernel(
    const int* __restrict__ qsrc, const int* __restrict__ qdst,
    const float* __restrict__ qw, const int* __restrict__ blockCount,
    const int* __restrict__ rowptr, int* __restrict__ fill,
    int* __restrict__ esrc, float* __restrict__ ew)
{
    const int b = blockIdx.x;
    const int cnt = blockCount[b];
    const int t = threadIdx.x;
    if (t < cnt) {
        const int i = b * 256 + t;
        const int dst = qdst[i];
        const int slot = rowptr[dst] + atomicAdd(fill + dst, 1);
        esrc[slot] = qsrc[i];
        ew[slot] = qw[i];
    }
}

// ---------------------------------------------------------------------------
// Gather layer 1 (one wave per node) + normalize + b1 + ReLU + W2 GEMV -> xp2.
// xp1 rows are bf16 (256 B): lane reads one uint = cols 2l, 2l+1.
// ---------------------------------------------------------------------------
__global__ __launch_bounds__(256) void gather1_kernel(
    const unsigned short* __restrict__ xp1, const float* __restrict__ denom1,
    const int* __restrict__ rowptr, const int* __restrict__ esrc,
    const float* __restrict__ ew,
    const float* __restrict__ b1, const float* __restrict__ W2,
    float* __restrict__ xp2)
{
    const int wid = threadIdx.x >> 6;
    const int lane = threadIdx.x & 63;
    const int i = blockIdx.x * 4 + wid;
    if (i >= N_NODES) return;

    const int begin = rowptr[i];
    const int end   = rowptr[i + 1];
    const float wself = denom1[i];

    const unsigned pself = ((const unsigned*)(xp1 + (size_t)i * HD))[lane];
    float a0 = wself * bf2f(pself & 0xFFFFu);
    float a1 = wself * bf2f(pself >> 16);
    float denom = wself;

    int sN = 0; float wN = 0.f;
    if (begin < end) { sN = esrc[begin]; wN = ew[begin]; }
    for (int j = begin; j < end; ++j) {
        const int s = sN; const float w = wN;
        if (j + 1 < end) { sN = esrc[j + 1]; wN = ew[j + 1]; }
        const unsigned pv = ((const unsigned*)(xp1 + (size_t)s * HD))[lane];
        a0 += w * bf2f(pv & 0xFFFFu);
        a1 += w * bf2f(pv >> 16);
        denom += w;
    }

    const float inv = 1.f / denom;
    const float o0 = fmaxf(a0 * inv + b1[2 * lane],     0.f);
    const float o1 = fmaxf(a1 * inv + b1[2 * lane + 1], 0.f);

    float part = o0 * W2[2 * lane] + o1 * W2[2 * lane + 1];
    #pragma unroll
    for (int off = 32; off > 0; off >>= 1) part += __shfl_down(part, off, 64);
    if (lane == 0) xp2[i] = part;
}

// ---------------------------------------------------------------------------
// Layer 2 over scalars (one thread per node): reuse the same CSR.
// ---------------------------------------------------------------------------
__global__ __launch_bounds__(256) void final2_kernel(
    const float* __restrict__ xp2, const int* __restrict__ rowptr,
    const int* __restrict__ esrc,
    const float* __restrict__ a_src2, const float* __restrict__ a_dst2,
    const float* __restrict__ b2, float* __restrict__ out)
{
    const int i = blockIdx.x * 256 + threadIdx.x;
    if (i >= N_NODES) return;

    const float as = a_src2[0], ad = a_dst2[0];
    const float xi = xp2[i];
    const float s0 = (as + ad) * xi;
    const float l0 = s0 > 0.f ? s0 : SLOPE * s0;
    const float wself = __expf(l0);

    float denom = wself, num = wself * xi;
    const int end = rowptr[i + 1];
    for (int j = rowptr[i]; j < end; ++j) {
        const float xsv = xp2[esrc[j]];
        const float lg = as * xsv + ad * xi;
        const float ll = lg > 0.f ? lg : SLOPE * lg;
        const float w = __expf(ll);
        denom += w;
        num += w * xsv;
    }
    out[i] = num / denom + b2[0];
}

extern "C" void kernel_launch(void* const* d_in, const int* in_sizes, int n_in,
                              void* d_out, int out_size, void* d_ws, size_t ws_size,
                              hipStream_t stream)
{
    const int* h   = (const int*)d_in[0];
    const int* ei  = (const int*)d_in[1];
    const int* nt  = (const int*)d_in[2];
    const float* emb    = (const float*)d_in[3];
    const float* W1     = (const float*)d_in[4];
    const float* a_src1 = (const float*)d_in[5];
    const float* a_dst1 = (const float*)d_in[6];
    const float* b1     = (const float*)d_in[7];
    const float* W2     = (const float*)d_in[8];
    const float* a_src2 = (const float*)d_in[9];
    const float* a_dst2 = (const float*)d_in[10];
    const float* b2     = (const float*)d_in[11];
    float* out = (float*)d_out;

    char* ws = (char*)d_ws;
    size_t off = 0;
    unsigned short* xp1 = (unsigned short*)(ws + off); off += (size_t)N_NODES * HD * sizeof(unsigned short);
    float* es1    = (float*)(ws + off); off += (size_t)N_NODES * sizeof(float);
    float* ed1    = (float*)(ws + off); off += (size_t)N_NODES * sizeof(float);
    float* denom1 = (float*)(ws + off); off += (size_t)N_NODES * sizeof(float);
    float* xp2    = (float*)(ws + off); off += (size_t)N_NODES * sizeof(float);
    int*   deg    = (int*)(ws + off);   off += (size_t)N_NODES * sizeof(int);
    int*   fill   = (int*)(ws + off);   off += (size_t)N_NODES * sizeof(int);
    int*   rowptr = (int*)(ws + off);   off += ((size_t)N_NODES + 1) * sizeof(int);
    int*   bsum   = (int*)(ws + off);   off += (size_t)NBLK * sizeof(int);
    int*   bscan  = (int*)(ws + off);   off += (size_t)NBLK * sizeof(int);
    int*   bcnt   = (int*)(ws + off);   off += (size_t)EBLK * sizeof(int);
    unsigned* umask = (unsigned*)(ws + off); off += 3200 * sizeof(unsigned);
    unsigned short* W1bfT = (unsigned short*)(ws + off); off += (size_t)HD * HD * sizeof(unsigned short);
    off = (off + 255) & ~(size_t)255;
    int*   qsrc   = (int*)(ws + off);   off += (size_t)N_EDGES * sizeof(int);
    int*   qdst   = (int*)(ws + off);   off += (size_t)N_EDGES * sizeof(int);
    float* qw     = (float*)(ws + off); off += (size_t)N_EDGES * sizeof(float);
    int*   esrc   = (int*)(ws + off);   off += (size_t)N_EDGES * sizeof(int);
    float* ew     = (float*)(ws + off); off += (size_t)N_EDGES * sizeof(float);

    prepw_kernel<<<HD, HD, 0, stream>>>(W1, W1bfT);
    zero_kernel<<<NBLK, 256, 0, stream>>>(nt, deg, fill, umask);
    gemm1_kernel<<<(N_NODES + 63) / 64, 256, 0, stream>>>(
        h, emb, W1bfT, a_src1, a_dst1, xp1, es1, ed1, denom1);
    edgeA_kernel<<<EBLK, 256, 0, stream>>>(
        ei, umask, es1, ed1, deg, bcnt, qsrc, qdst, qw);
    bsum_kernel<<<NBLK, 256, 0, stream>>>(deg, bsum);
    bscan_kernel<<<1, 512, 0, stream>>>(bsum, bscan, rowptr);
    rowptr_kernel<<<NBLK, 256, 0, stream>>>(deg, bscan, rowptr);
    scatterB_kernel<<<EBLK, 256, 0, stream>>>(
        qsrc, qdst, qw, bcnt, rowptr, fill, esrc, ew);
    gather1_kernel<<<(N_NODES + 3) / 4, 256, 0, stream>>>(
        xp1, denom1, rowptr, esrc, ew, b1, W2, xp2);
    final2_kernel<<<NBLK, 256, 0, stream>>>(
        xp2, rowptr, esrc, a_src2, a_dst2, b2, out);
}

// Round 11
// 204.576 us; speedup vs baseline: 2.5089x; 1.0735x over previous
//
#include <hip/hip_runtime.h>

#define N_NODES 100000
#define N_EDGES 1600000
#define HD 128
#define SLOPE 0.2f
#define NBLK 391  // ceil(N_NODES/256)
#define EBLK (N_EDGES / 256)   // 6250 edge blocks

typedef __attribute__((ext_vector_type(8))) short bf16x8;
typedef __attribute__((ext_vector_type(4))) float f32x4;

__device__ __forceinline__ unsigned short f2bf(float f) {
    union { float f; unsigned u; } v; v.f = f;
    const unsigned u = v.u + 0x7FFFu + ((v.u >> 16) & 1u);   // RNE
    return (unsigned short)(u >> 16);
}
__device__ __forceinline__ unsigned pack2(float lo, float hi) {
    return (unsigned)f2bf(lo) | ((unsigned)f2bf(hi) << 16);
}
__device__ __forceinline__ float bf2f(unsigned u16) {
    union { unsigned u; float f; } v; v.u = u16 << 16; return v.f;
}

// ---------------------------------------------------------------------------
// P0: W1bfT[n][k] = bf16(W1[k][n]) — one-time transpose+convert (32 KB, L2-hot).
// ---------------------------------------------------------------------------
__global__ __launch_bounds__(128) void prepw_kernel(
    const float* __restrict__ W1, unsigned short* __restrict__ W1bfT)
{
    const int n = blockIdx.x;
    const int k = threadIdx.x;
    W1bfT[n * HD + k] = f2bf(W1[k * HD + n]);
}

// ---------------------------------------------------------------------------
// K0: zero deg/fill + build node-active bitmask (12.5 KB -> L1-resident).
// ---------------------------------------------------------------------------
__global__ __launch_bounds__(256) void zero_kernel(
    const int* __restrict__ nt,
    int* __restrict__ deg, int* __restrict__ fill, unsigned* __restrict__ umask)
{
    const int i = blockIdx.x * 256 + threadIdx.x;
    bool act = false;
    if (i < N_NODES) { deg[i] = 0; fill[i] = 0; act = (nt[i] == 0); }
    const unsigned long long bal = __ballot(act);
    const int lane = threadIdx.x & 63;
    if (lane == 0)       umask[i >> 5] = (unsigned)bal;
    else if (lane == 32) umask[i >> 5] = (unsigned)(bal >> 32);
}

// ---------------------------------------------------------------------------
// K1: xp1 = emb[h] @ W1 via bf16 MFMA 16x16x32 — B staged in LDS.
// r10 lesson: B-frags straight from global serialize on ~200-cyc L2 latency
// under a 64-VGPR budget. Fix: copy the 32 KB bf16 W^T into LDS once per
// block (no transpose/convert — prepw did it), so the 32 B-frag reads per
// wave are ~12-cyc ds_read_b128. Chunk index XOR-swizzled by n&7 for bank
// spread. Only global traffic left: the coalesced A-stream.
// Block = 64 rows; wave = 16 rows x all 128 cols (acc[8], in-wave es/ed
// reduce, no epilogue barrier). xp1 stored bf16.
// ---------------------------------------------------------------------------
__global__ __launch_bounds__(256) void gemm1_kernel(
    const int* __restrict__ h,
    const float* __restrict__ emb,
    const unsigned short* __restrict__ W1bfT,
    const float* __restrict__ a_src1,
    const float* __restrict__ a_dst1,
    unsigned short* __restrict__ xp1,
    float* __restrict__ es1,
    float* __restrict__ ed1,
    float* __restrict__ denom1)
{
    __shared__ unsigned short Wlds[HD * HD];   // 32 KB

    const int tid = threadIdx.x;

    // ---- stage W^T: thread t -> col n = t>>1, k-half (t&1)*64, swizzled ----
    {
        const int n  = tid >> 1;
        const int kh = (tid & 1) * 64;
        const unsigned short* src = W1bfT + n * HD + kh;
        #pragma unroll
        for (int j = 0; j < 8; ++j) {
            const int c = (kh >> 3) + j;               // 16B chunk index along k
            const int p = c ^ (n & 7);                 // swizzle
            *(bf16x8*)(Wlds + n * HD + p * 8) = *(const bf16x8*)(src + j * 8);
        }
    }

    const int w   = tid >> 6;
    const int L   = tid & 63;
    const int lm  = L & 15;
    const int lg  = L >> 4;
    const int wrow0 = blockIdx.x * 64 + w * 16;

    const int arow = wrow0 + lm;
    const int g = (arow < N_NODES) ? arow : (N_NODES - 1);
    const float* xrow = emb + (size_t)h[g] * HD;

    __syncthreads();

    f32x4 acc[8];
    #pragma unroll
    for (int ct = 0; ct < 8; ++ct) acc[ct] = (f32x4)0.f;

    #pragma unroll
    for (int ks = 0; ks < 4; ++ks) {
        const int k0 = ks * 32 + lg * 8;
        const float4 u = *(const float4*)(xrow + k0);
        const float4 v = *(const float4*)(xrow + k0 + 4);
        union { bf16x8 b; unsigned x[4]; } t;
        t.x[0] = pack2(u.x, u.y);
        t.x[1] = pack2(u.z, u.w);
        t.x[2] = pack2(v.x, v.y);
        t.x[3] = pack2(v.z, v.w);
        const bf16x8 af = t.b;

        const int c = k0 >> 3;                         // chunk index
        const int p = (c ^ (lm & 7)) * 8;              // swizzled offset (n&7==lm&7)
        #pragma unroll
        for (int ct = 0; ct < 8; ++ct) {
            const bf16x8 bfr = *(const bf16x8*)(Wlds + (ct * 16 + lm) * HD + p);
            acc[ct] = __builtin_amdgcn_mfma_f32_16x16x32_bf16(af, bfr, acc[ct], 0, 0, 0);
        }
    }

    // ---- attention dots + store (C/D: col = lm, row-in-tile = lg*4+reg) ----
    float asv[8], adv[8];
    #pragma unroll
    for (int ct = 0; ct < 8; ++ct) {
        asv[ct] = a_src1[ct * 16 + lm];
        adv[ct] = a_dst1[ct * 16 + lm];
    }

    #pragma unroll
    for (int reg = 0; reg < 4; ++reg) {
        const int row = wrow0 + lg * 4 + reg;
        float s = 0.f, d = 0.f;
        #pragma unroll
        for (int ct = 0; ct < 8; ++ct) {
            s += acc[ct][reg] * asv[ct];
            d += acc[ct][reg] * adv[ct];
        }
        #pragma unroll
        for (int m = 1; m < 16; m <<= 1) {   // reduce over the 16 lm lanes
            s += __shfl_xor(s, m, 64);
            d += __shfl_xor(d, m, 64);
        }
        if (row < N_NODES) {
            unsigned short* dst = xp1 + (size_t)row * HD;
            #pragma unroll
            for (int ct = 0; ct < 8; ++ct)
                dst[ct * 16 + lm] = f2bf(acc[ct][reg]);
            if (lm == 0) {
                const float sum = s + d;
                const float l = sum > 0.f ? sum : SLOPE * sum;
                es1[row] = s;
                ed1[row] = d;
                denom1[row] = __expf(l);
            }
        }
    }
}

// ---------------------------------------------------------------------------
// Pass A: gate via L1-resident bitmask + deg histogram + block-local compaction.
// ---------------------------------------------------------------------------
__global__ __launch_bounds__(256) void edgeA_kernel(
    const int* __restrict__ ei, const unsigned* __restrict__ umask,
    const float* __restrict__ es1, const float* __restrict__ ed1,
    int* __restrict__ deg, int* __restrict__ blockCount,
    int* __restrict__ qsrc, int* __restrict__ qdst, float* __restrict__ qw)
{
    __shared__ int wcnt[4];
    const int e = blockIdx.x * 256 + threadIdx.x;
    const int wid = threadIdx.x >> 6;
    const int lane = threadIdx.x & 63;

    const int src = ei[e];
    const int dst = ei[N_EDGES + e];
    const bool active =
        (((umask[src >> 5] >> (src & 31)) & (umask[dst >> 5] >> (dst & 31))) & 1u) != 0u;

    const unsigned long long bal = __ballot(active);
    if (lane == 0) wcnt[wid] = (int)__popcll(bal);
    __syncthreads();
    const int c0w = wcnt[0], c1w = wcnt[1], c2w = wcnt[2], c3w = wcnt[3];
    if (threadIdx.x == 0) blockCount[blockIdx.x] = c0w + c1w + c2w + c3w;

    if (active) {
        int base = 0;
        if (wid > 0) base += c0w;
        if (wid > 1) base += c1w;
        if (wid > 2) base += c2w;
        atomicAdd(deg + dst, 1);
        const float logit = es1[src] + ed1[dst];
        const float l = logit > 0.f ? logit : SLOPE * logit;
        const int slot = blockIdx.x * 256 + base +
                         (int)__popcll(bal & ((1ull << lane) - 1ull));
        qsrc[slot] = src;
        qdst[slot] = dst;
        qw[slot] = __expf(l);
    }
}

// ---------------------------------------------------------------------------
// scans: block sums -> block scan -> rowptr
// ---------------------------------------------------------------------------
__global__ __launch_bounds__(256) void bsum_kernel(
    const int* __restrict__ deg, int* __restrict__ bsum)
{
    __shared__ int wsum[4];
    const int i = blockIdx.x * 256 + threadIdx.x;
    int v = (i < N_NODES) ? deg[i] : 0;
    #pragma unroll
    for (int off = 32; off > 0; off >>= 1) v += __shfl_down(v, off, 64);
    if ((threadIdx.x & 63) == 0) wsum[threadIdx.x >> 6] = v;
    __syncthreads();
    if (threadIdx.x == 0) bsum[blockIdx.x] = wsum[0] + wsum[1] + wsum[2] + wsum[3];
}

__global__ __launch_bounds__(512) void bscan_kernel(
    const int* __restrict__ bsum, int* __restrict__ bscan, int* __restrict__ rowptr)
{
    __shared__ int s[512];
    const int t = threadIdx.x;
    const int v = (t < NBLK) ? bsum[t] : 0;
    s[t] = v;
    __syncthreads();
    #pragma unroll
    for (int off = 1; off < 512; off <<= 1) {
        const int u = (t >= off) ? s[t - off] : 0;
        __syncthreads();
        s[t] += u;
        __syncthreads();
    }
    if (t < NBLK) bscan[t] = s[t] - v;
    if (t == 0) rowptr[N_NODES] = s[NBLK - 1];
}

__global__ __launch_bounds__(256) void rowptr_kernel(
    const int* __restrict__ deg, const int* __restrict__ bscan, int* __restrict__ rowptr)
{
    __shared__ int s[256];
    const int t = threadIdx.x;
    const int i = blockIdx.x * 256 + t;
    const int v = (i < N_NODES) ? deg[i] : 0;
    s[t] = v;
    __syncthreads();
    #pragma unroll
    for (int off = 1; off < 256; off <<= 1) {
        const int u = (t >= off) ? s[t - off] : 0;
        __syncthreads();
        s[t] += u;
        __syncthreads();
    }
    if (i < N_NODES) rowptr[i] = bscan[blockIdx.x] + s[t] - v;
}

// ---------------------------------------------------------------------------
// Pass B: place survivors into CSR slots (fill atomics spread over 100K addrs).
// ---------------------------------------------------------------------------
__global__ __launch_bounds__(256) void scatterB_kernel(
    const int* __restrict__ qsrc, const int* __restrict__ qdst,
    const float* __restrict__ qw, const int* __restrict__ blockCount,
    const int* __restrict__ rowptr, int* __restrict__ fill,
    int* __restrict__ esrc, float* __restrict__ ew)
{
    const int b = blockIdx.x;
    const int cnt = blockCount[b];
    const int t = threadIdx.x;
    if (t < cnt) {
        const int i = b * 256 + t;
        const int dst = qdst[i];
        const int slot = rowptr[dst] + atomicAdd(fill + dst, 1);
        esrc[slot] = qsrc[i];
        ew[slot] = qw[i];
    }
}

// ---------------------------------------------------------------------------
// Gather layer 1 (one wave per node) + normalize + b1 + ReLU + W2 GEMV -> xp2.
// xp1 rows are bf16 (256 B): lane reads one uint = cols 2l, 2l+1.
// ---------------------------------------------------------------------------
__global__ __launch_bounds__(256) void gather1_kernel(
    const unsigned short* __restrict__ xp1, const float* __restrict__ denom1,
    const int* __restrict__ rowptr, const int* __restrict__ esrc,
    const float* __restrict__ ew,
    const float* __restrict__ b1, const float* __restrict__ W2,
    float* __restrict__ xp2)
{
    const int wid = threadIdx.x >> 6;
    const int lane = threadIdx.x & 63;
    const int i = blockIdx.x * 4 + wid;
    if (i >= N_NODES) return;

    const int begin = rowptr[i];
    const int end   = rowptr[i + 1];
    const float wself = denom1[i];

    const unsigned pself = ((const unsigned*)(xp1 + (size_t)i * HD))[lane];
    float a0 = wself * bf2f(pself & 0xFFFFu);
    float a1 = wself * bf2f(pself >> 16);
    float denom = wself;

    int sN = 0; float wN = 0.f;
    if (begin < end) { sN = esrc[begin]; wN = ew[begin]; }
    for (int j = begin; j < end; ++j) {
        const int s = sN; const float w = wN;
        if (j + 1 < end) { sN = esrc[j + 1]; wN = ew[j + 1]; }
        const unsigned pv = ((const unsigned*)(xp1 + (size_t)s * HD))[lane];
        a0 += w * bf2f(pv & 0xFFFFu);
        a1 += w * bf2f(pv >> 16);
        denom += w;
    }

    const float inv = 1.f / denom;
    const float o0 = fmaxf(a0 * inv + b1[2 * lane],     0.f);
    const float o1 = fmaxf(a1 * inv + b1[2 * lane + 1], 0.f);

    float part = o0 * W2[2 * lane] + o1 * W2[2 * lane + 1];
    #pragma unroll
    for (int off = 32; off > 0; off >>= 1) part += __shfl_down(part, off, 64);
    if (lane == 0) xp2[i] = part;
}

// ---------------------------------------------------------------------------
// Layer 2 over scalars (one thread per node): reuse the same CSR.
// ---------------------------------------------------------------------------
__global__ __launch_bounds__(256) void final2_kernel(
    const float* __restrict__ xp2, const int* __restrict__ rowptr,
    const int* __restrict__ esrc,
    const float* __restrict__ a_src2, const float* __restrict__ a_dst2,
    const float* __restrict__ b2, float* __restrict__ out)
{
    const int i = blockIdx.x * 256 + threadIdx.x;
    if (i >= N_NODES) return;

    const float as = a_src2[0], ad = a_dst2[0];
    const float xi = xp2[i];
    const float s0 = (as + ad) * xi;
    const float l0 = s0 > 0.f ? s0 : SLOPE * s0;
    const float wself = __expf(l0);

    float denom = wself, num = wself * xi;
    const int end = rowptr[i + 1];
    for (int j = rowptr[i]; j < end; ++j) {
        const float xsv = xp2[esrc[j]];
        const float lg = as * xsv + ad * xi;
        const float ll = lg > 0.f ? lg : SLOPE * lg;
        const float w = __expf(ll);
        denom += w;
        num += w * xsv;
    }
    out[i] = num / denom + b2[0];
}

extern "C" void kernel_launch(void* const* d_in, const int* in_sizes, int n_in,
                              void* d_out, int out_size, void* d_ws, size_t ws_size,
                              hipStream_t stream)
{
    const int* h   = (const int*)d_in[0];
    const int* ei  = (const int*)d_in[1];
    const int* nt  = (const int*)d_in[2];
    const float* emb    = (const float*)d_in[3];
    const float* W1     = (const float*)d_in[4];
    const float* a_src1 = (const float*)d_in[5];
    const float* a_dst1 = (const float*)d_in[6];
    const float* b1     = (const float*)d_in[7];
    const float* W2     = (const float*)d_in[8];
    const float* a_src2 = (const float*)d_in[9];
    const float* a_dst2 = (const float*)d_in[10];
    const float* b2     = (const float*)d_in[11];
    float* out = (float*)d_out;

    char* ws = (char*)d_ws;
    size_t off = 0;
    unsigned short* xp1 = (unsigned short*)(ws + off); off += (size_t)N_NODES * HD * sizeof(unsigned short);
    float* es1    = (float*)(ws + off); off += (size_t)N_NODES * sizeof(float);
    float* ed1    = (float*)(ws + off); off += (size_t)N_NODES * sizeof(float);
    float* denom1 = (float*)(ws + off); off += (size_t)N_NODES * sizeof(float);
    float* xp2    = (float*)(ws + off); off += (size_t)N_NODES * sizeof(float);
    int*   deg    = (int*)(ws + off);   off += (size_t)N_NODES * sizeof(int);
    int*   fill   = (int*)(ws + off);   off += (size_t)N_NODES * sizeof(int);
    int*   rowptr = (int*)(ws + off);   off += ((size_t)N_NODES + 1) * sizeof(int);
    int*   bsum   = (int*)(ws + off);   off += (size_t)NBLK * sizeof(int);
    int*   bscan  = (int*)(ws + off);   off += (size_t)NBLK * sizeof(int);
    int*   bcnt   = (int*)(ws + off);   off += (size_t)EBLK * sizeof(int);
    unsigned* umask = (unsigned*)(ws + off); off += 3200 * sizeof(unsigned);
    unsigned short* W1bfT = (unsigned short*)(ws + off); off += (size_t)HD * HD * sizeof(unsigned short);
    off = (off + 255) & ~(size_t)255;
    int*   qsrc   = (int*)(ws + off);   off += (size_t)N_EDGES * sizeof(int);
    int*   qdst   = (int*)(ws + off);   off += (size_t)N_EDGES * sizeof(int);
    float* qw     = (float*)(ws + off); off += (size_t)N_EDGES * sizeof(float);
    int*   esrc   = (int*)(ws + off);   off += (size_t)N_EDGES * sizeof(int);
    float* ew     = (float*)(ws + off); off += (size_t)N_EDGES * sizeof(float);

    prepw_kernel<<<HD, HD, 0, stream>>>(W1, W1bfT);
    zero_kernel<<<NBLK, 256, 0, stream>>>(nt, deg, fill, umask);
    gemm1_kernel<<<(N_NODES + 63) / 64, 256, 0, stream>>>(
        h, emb, W1bfT, a_src1, a_dst1, xp1, es1, ed1, denom1);
    edgeA_kernel<<<EBLK, 256, 0, stream>>>(
        ei, umask, es1, ed1, deg, bcnt, qsrc, qdst, qw);
    bsum_kernel<<<NBLK, 256, 0, stream>>>(deg, bsum);
    bscan_kernel<<<1, 512, 0, stream>>>(bsum, bscan, rowptr);
    rowptr_kernel<<<NBLK, 256, 0, stream>>>(deg, bscan, rowptr);
    scatterB_kernel<<<EBLK, 256, 0, stream>>>(
        qsrc, qdst, qw, bcnt, rowptr, fill, esrc, ew);
    gather1_kernel<<<(N_NODES + 3) / 4, 256, 0, stream>>>(
        xp1, denom1, rowptr, esrc, ew, b1, W2, xp2);
    final2_kernel<<<NBLK, 256, 0, stream>>>(
        xp2, rowptr, esrc, a_src2, a_dst2, b2, out);
}

// Round 12
// 202.280 us; speedup vs baseline: 2.5374x; 1.0113x over previous
//
#include <hip/hip_runtime.h>

#define N_NODES 100000
#define N_EDGES 1600000
#define HD 128
#define SLOPE 0.2f
#define NBLK 391  // ceil(N_NODES/256)
#define EBLK (N_EDGES / 256)   // 6250 edge blocks

typedef __attribute__((ext_vector_type(8))) short bf16x8;
typedef __attribute__((ext_vector_type(4))) float f32x4;

__device__ __forceinline__ unsigned short f2bf(float f) {
    union { float f; unsigned u; } v; v.f = f;
    const unsigned u = v.u + 0x7FFFu + ((v.u >> 16) & 1u);   // RNE
    return (unsigned short)(u >> 16);
}
__device__ __forceinline__ unsigned pack2(float lo, float hi) {
    return (unsigned)f2bf(lo) | ((unsigned)f2bf(hi) << 16);
}
__device__ __forceinline__ float bf2f(unsigned u16) {
    union { unsigned u; float f; } v; v.u = u16 << 16; return v.f;
}

// ---------------------------------------------------------------------------
// K0: zero deg/fill + node-active bitmask + W1^T bf16 convert (prepw merged).
// ---------------------------------------------------------------------------
__global__ __launch_bounds__(256) void zero_kernel(
    const int* __restrict__ nt, const float* __restrict__ W1,
    int* __restrict__ deg, int* __restrict__ fill, unsigned* __restrict__ umask,
    unsigned short* __restrict__ W1bfT)
{
    const int i = blockIdx.x * 256 + threadIdx.x;
    bool act = false;
    if (i < N_NODES) { deg[i] = 0; fill[i] = 0; act = (nt[i] == 0); }
    const unsigned long long bal = __ballot(act);
    const int lane = threadIdx.x & 63;
    if (lane == 0)       umask[i >> 5] = (unsigned)bal;
    else if (lane == 32) umask[i >> 5] = (unsigned)(bal >> 32);
    if (i < HD * HD) {
        const int n = i >> 7, k = i & 127;
        W1bfT[n * HD + k] = f2bf(W1[k * HD + n]);
    }
}

// ---------------------------------------------------------------------------
// K1: xp1 = emb[h] @ W1 via bf16 MFMA 16x16x32 — B in LDS, FULL occupancy.
// 512-thread blocks (8 waves), 128 rows/block, 32 KB LDS -> 4 blocks/CU
// = 32 waves/CU (hardware max; r11 had 20). Wave = 16 rows x all 128 cols,
// in-wave es/ed reduce, bf16 xp1 store. (512,8) pins the 64-VGPR budget.
// ---------------------------------------------------------------------------
__global__ __launch_bounds__(512, 8) void gemm1_kernel(
    const int* __restrict__ h,
    const float* __restrict__ emb,
    const unsigned short* __restrict__ W1bfT,
    const float* __restrict__ a_src1,
    const float* __restrict__ a_dst1,
    unsigned short* __restrict__ xp1,
    float* __restrict__ es1,
    float* __restrict__ ed1,
    float* __restrict__ denom1)
{
    __shared__ unsigned short Wlds[HD * HD];   // 32 KB

    const int tid = threadIdx.x;

    // ---- stage W^T: thread t -> col n = t>>2, k-quarter (t&3)*32, swizzled ----
    {
        const int n  = tid >> 2;
        const int kq = (tid & 3) * 32;
        const unsigned short* src = W1bfT + n * HD + kq;
        #pragma unroll
        for (int j = 0; j < 4; ++j) {
            const int c = (kq >> 3) + j;               // 16B chunk index along k
            const int p = c ^ (n & 7);                 // swizzle
            *(bf16x8*)(Wlds + n * HD + p * 8) = *(const bf16x8*)(src + j * 8);
        }
    }

    const int w   = tid >> 6;                          // 0..7
    const int L   = tid & 63;
    const int lm  = L & 15;
    const int lg  = L >> 4;
    const int wrow0 = blockIdx.x * 128 + w * 16;

    const int arow = wrow0 + lm;
    const int g = (arow < N_NODES) ? arow : (N_NODES - 1);
    const float* xrow = emb + (size_t)h[g] * HD;

    __syncthreads();

    f32x4 acc[8];
    #pragma unroll
    for (int ct = 0; ct < 8; ++ct) acc[ct] = (f32x4)0.f;

    #pragma unroll
    for (int ks = 0; ks < 4; ++ks) {
        const int k0 = ks * 32 + lg * 8;
        const float4 u = *(const float4*)(xrow + k0);
        const float4 v = *(const float4*)(xrow + k0 + 4);
        union { bf16x8 b; unsigned x[4]; } t;
        t.x[0] = pack2(u.x, u.y);
        t.x[1] = pack2(u.z, u.w);
        t.x[2] = pack2(v.x, v.y);
        t.x[3] = pack2(v.z, v.w);
        const bf16x8 af = t.b;

        const int c = k0 >> 3;
        const int p = (c ^ (lm & 7)) * 8;              // n&7 == lm&7 for frag reads
        #pragma unroll
        for (int ct = 0; ct < 8; ++ct) {
            const bf16x8 bfr = *(const bf16x8*)(Wlds + (ct * 16 + lm) * HD + p);
            acc[ct] = __builtin_amdgcn_mfma_f32_16x16x32_bf16(af, bfr, acc[ct], 0, 0, 0);
        }
    }

    // ---- attention dots + store (C/D: col = lm, row-in-tile = lg*4+reg) ----
    float asv[8], adv[8];
    #pragma unroll
    for (int ct = 0; ct < 8; ++ct) {
        asv[ct] = a_src1[ct * 16 + lm];
        adv[ct] = a_dst1[ct * 16 + lm];
    }

    #pragma unroll
    for (int reg = 0; reg < 4; ++reg) {
        const int row = wrow0 + lg * 4 + reg;
        float s = 0.f, d = 0.f;
        #pragma unroll
        for (int ct = 0; ct < 8; ++ct) {
            s += acc[ct][reg] * asv[ct];
            d += acc[ct][reg] * adv[ct];
        }
        #pragma unroll
        for (int m = 1; m < 16; m <<= 1) {   // reduce over the 16 lm lanes
            s += __shfl_xor(s, m, 64);
            d += __shfl_xor(d, m, 64);
        }
        if (row < N_NODES) {
            unsigned short* dst = xp1 + (size_t)row * HD;
            #pragma unroll
            for (int ct = 0; ct < 8; ++ct)
                dst[ct * 16 + lm] = f2bf(acc[ct][reg]);
            if (lm == 0) {
                const float sum = s + d;
                const float l = sum > 0.f ? sum : SLOPE * sum;
                es1[row] = s;
                ed1[row] = d;
                denom1[row] = __expf(l);
            }
        }
    }
}

// ---------------------------------------------------------------------------
// Pass A: gate via L1-resident bitmask + deg histogram + block-local compaction.
// ---------------------------------------------------------------------------
__global__ __launch_bounds__(256) void edgeA_kernel(
    const int* __restrict__ ei, const unsigned* __restrict__ umask,
    const float* __restrict__ es1, const float* __restrict__ ed1,
    int* __restrict__ deg, int* __restrict__ blockCount,
    int* __restrict__ qsrc, int* __restrict__ qdst, float* __restrict__ qw)
{
    __shared__ int wcnt[4];
    const int e = blockIdx.x * 256 + threadIdx.x;
    const int wid = threadIdx.x >> 6;
    const int lane = threadIdx.x & 63;

    const int src = ei[e];
    const int dst = ei[N_EDGES + e];
    const bool active =
        (((umask[src >> 5] >> (src & 31)) & (umask[dst >> 5] >> (dst & 31))) & 1u) != 0u;

    const unsigned long long bal = __ballot(active);
    if (lane == 0) wcnt[wid] = (int)__popcll(bal);
    __syncthreads();
    const int c0w = wcnt[0], c1w = wcnt[1], c2w = wcnt[2], c3w = wcnt[3];
    if (threadIdx.x == 0) blockCount[blockIdx.x] = c0w + c1w + c2w + c3w;

    if (active) {
        int base = 0;
        if (wid > 0) base += c0w;
        if (wid > 1) base += c1w;
        if (wid > 2) base += c2w;
        atomicAdd(deg + dst, 1);
        const float logit = es1[src] + ed1[dst];
        const float l = logit > 0.f ? logit : SLOPE * logit;
        const int slot = blockIdx.x * 256 + base +
                         (int)__popcll(bal & ((1ull << lane) - 1ull));
        qsrc[slot] = src;
        qdst[slot] = dst;
        qw[slot] = __expf(l);
    }
}

// ---------------------------------------------------------------------------
// scans: block sums -> block scan -> rowptr
// ---------------------------------------------------------------------------
__global__ __launch_bounds__(256) void bsum_kernel(
    const int* __restrict__ deg, int* __restrict__ bsum)
{
    __shared__ int wsum[4];
    const int i = blockIdx.x * 256 + threadIdx.x;
    int v = (i < N_NODES) ? deg[i] : 0;
    #pragma unroll
    for (int off = 32; off > 0; off >>= 1) v += __shfl_down(v, off, 64);
    if ((threadIdx.x & 63) == 0) wsum[threadIdx.x >> 6] = v;
    __syncthreads();
    if (threadIdx.x == 0) bsum[blockIdx.x] = wsum[0] + wsum[1] + wsum[2] + wsum[3];
}

__global__ __launch_bounds__(512) void bscan_kernel(
    const int* __restrict__ bsum, int* __restrict__ bscan, int* __restrict__ rowptr)
{
    __shared__ int s[512];
    const int t = threadIdx.x;
    const int v = (t < NBLK) ? bsum[t] : 0;
    s[t] = v;
    __syncthreads();
    #pragma unroll
    for (int off = 1; off < 512; off <<= 1) {
        const int u = (t >= off) ? s[t - off] : 0;
        __syncthreads();
        s[t] += u;
        __syncthreads();
    }
    if (t < NBLK) bscan[t] = s[t] - v;
    if (t == 0) rowptr[N_NODES] = s[NBLK - 1];
}

__global__ __launch_bounds__(256) void rowptr_kernel(
    const int* __restrict__ deg, const int* __restrict__ bscan, int* __restrict__ rowptr)
{
    __shared__ int s[256];
    const int t = threadIdx.x;
    const int i = blockIdx.x * 256 + t;
    const int v = (i < N_NODES) ? deg[i] : 0;
    s[t] = v;
    __syncthreads();
    #pragma unroll
    for (int off = 1; off < 256; off <<= 1) {
        const int u = (t >= off) ? s[t - off] : 0;
        __syncthreads();
        s[t] += u;
        __syncthreads();
    }
    if (i < N_NODES) rowptr[i] = bscan[blockIdx.x] + s[t] - v;
}

// ---------------------------------------------------------------------------
// Pass B: place survivors into CSR slots — grid-stride over segments
// (r11 launched 6250 blocks at ~11% lane occupancy).
// ---------------------------------------------------------------------------
__global__ __launch_bounds__(256) void scatterB_kernel(
    const int* __restrict__ qsrc, const int* __restrict__ qdst,
    const float* __restrict__ qw, const int* __restrict__ blockCount,
    const int* __restrict__ rowptr, int* __restrict__ fill,
    int* __restrict__ esrc, float* __restrict__ ew)
{
    const int t = threadIdx.x;
    for (int b = blockIdx.x; b < EBLK; b += gridDim.x) {
        const int cnt = blockCount[b];
        if (t < cnt) {
            const int i = b * 256 + t;
            const int dst = qdst[i];
            const int slot = rowptr[dst] + atomicAdd(fill + dst, 1);
            esrc[slot] = qsrc[i];
            ew[slot] = qw[i];
        }
    }
}

// ---------------------------------------------------------------------------
// Gather layer 1 (one wave per node) + normalize + b1 + ReLU + W2 GEMV -> xp2.
// ---------------------------------------------------------------------------
__global__ __launch_bounds__(256) void gather1_kernel(
    const unsigned short* __restrict__ xp1, const float* __restrict__ denom1,
    const int* __restrict__ rowptr, const int* __restrict__ esrc,
    const float* __restrict__ ew,
    const float* __restrict__ b1, const float* __restrict__ W2,
    float* __restrict__ xp2)
{
    const int wid = threadIdx.x >> 6;
    const int lane = threadIdx.x & 63;
    const int i = blockIdx.x * 4 + wid;
    if (i >= N_NODES) return;

    const int begin = rowptr[i];
    const int end   = rowptr[i + 1];
    const float wself = denom1[i];

    const unsigned pself = ((const unsigned*)(xp1 + (size_t)i * HD))[lane];
    float a0 = wself * bf2f(pself & 0xFFFFu);
    float a1 = wself * bf2f(pself >> 16);
    float denom = wself;

    int sN = 0; float wN = 0.f;
    if (begin < end) { sN = esrc[begin]; wN = ew[begin]; }
    for (int j = begin; j < end; ++j) {
        const int s = sN; const float w = wN;
        if (j + 1 < end) { sN = esrc[j + 1]; wN = ew[j + 1]; }
        const unsigned pv = ((const unsigned*)(xp1 + (size_t)s * HD))[lane];
        a0 += w * bf2f(pv & 0xFFFFu);
        a1 += w * bf2f(pv >> 16);
        denom += w;
    }

    const float inv = 1.f / denom;
    const float o0 = fmaxf(a0 * inv + b1[2 * lane],     0.f);
    const float o1 = fmaxf(a1 * inv + b1[2 * lane + 1], 0.f);

    float part = o0 * W2[2 * lane] + o1 * W2[2 * lane + 1];
    #pragma unroll
    for (int off = 32; off > 0; off >>= 1) part += __shfl_down(part, off, 64);
    if (lane == 0) xp2[i] = part;
}

// ---------------------------------------------------------------------------
// Layer 2 over scalars (one thread per node): reuse the same CSR.
// ---------------------------------------------------------------------------
__global__ __launch_bounds__(256) void final2_kernel(
    const float* __restrict__ xp2, const int* __restrict__ rowptr,
    const int* __restrict__ esrc,
    const float* __restrict__ a_src2, const float* __restrict__ a_dst2,
    const float* __restrict__ b2, float* __restrict__ out)
{
    const int i = blockIdx.x * 256 + threadIdx.x;
    if (i >= N_NODES) return;

    const float as = a_src2[0], ad = a_dst2[0];
    const float xi = xp2[i];
    const float s0 = (as + ad) * xi;
    const float l0 = s0 > 0.f ? s0 : SLOPE * s0;
    const float wself = __expf(l0);

    float denom = wself, num = wself * xi;
    const int end = rowptr[i + 1];
    for (int j = rowptr[i]; j < end; ++j) {
        const float xsv = xp2[esrc[j]];
        const float lg = as * xsv + ad * xi;
        const float ll = lg > 0.f ? lg : SLOPE * lg;
        const float w = __expf(ll);
        denom += w;
        num += w * xsv;
    }
    out[i] = num / denom + b2[0];
}

extern "C" void kernel_launch(void* const* d_in, const int* in_sizes, int n_in,
                              void* d_out, int out_size, void* d_ws, size_t ws_size,
                              hipStream_t stream)
{
    const int* h   = (const int*)d_in[0];
    const int* ei  = (const int*)d_in[1];
    const int* nt  = (const int*)d_in[2];
    const float* emb    = (const float*)d_in[3];
    const float* W1     = (const float*)d_in[4];
    const float* a_src1 = (const float*)d_in[5];
    const float* a_dst1 = (const float*)d_in[6];
    const float* b1     = (const float*)d_in[7];
    const float* W2     = (const float*)d_in[8];
    const float* a_src2 = (const float*)d_in[9];
    const float* a_dst2 = (const float*)d_in[10];
    const float* b2     = (const float*)d_in[11];
    float* out = (float*)d_out;

    char* ws = (char*)d_ws;
    size_t off = 0;
    unsigned short* xp1 = (unsigned short*)(ws + off); off += (size_t)N_NODES * HD * sizeof(unsigned short);
    float* es1    = (float*)(ws + off); off += (size_t)N_NODES * sizeof(float);
    float* ed1    = (float*)(ws + off); off += (size_t)N_NODES * sizeof(float);
    float* denom1 = (float*)(ws + off); off += (size_t)N_NODES * sizeof(float);
    float* xp2    = (float*)(ws + off); off += (size_t)N_NODES * sizeof(float);
    int*   deg    = (int*)(ws + off);   off += (size_t)N_NODES * sizeof(int);
    int*   fill   = (int*)(ws + off);   off += (size_t)N_NODES * sizeof(int);
    int*   rowptr = (int*)(ws + off);   off += ((size_t)N_NODES + 1) * sizeof(int);
    int*   bsum   = (int*)(ws + off);   off += (size_t)NBLK * sizeof(int);
    int*   bscan  = (int*)(ws + off);   off += (size_t)NBLK * sizeof(int);
    int*   bcnt   = (int*)(ws + off);   off += (size_t)EBLK * sizeof(int);
    unsigned* umask = (unsigned*)(ws + off); off += 3200 * sizeof(unsigned);
    unsigned short* W1bfT = (unsigned short*)(ws + off); off += (size_t)HD * HD * sizeof(unsigned short);
    off = (off + 255) & ~(size_t)255;
    int*   qsrc   = (int*)(ws + off);   off += (size_t)N_EDGES * sizeof(int);
    int*   qdst   = (int*)(ws + off);   off += (size_t)N_EDGES * sizeof(int);
    float* qw     = (float*)(ws + off); off += (size_t)N_EDGES * sizeof(float);
    int*   esrc   = (int*)(ws + off);   off += (size_t)N_EDGES * sizeof(int);
    float* ew     = (float*)(ws + off); off += (size_t)N_EDGES * sizeof(float);

    zero_kernel<<<NBLK, 256, 0, stream>>>(nt, W1, deg, fill, umask, W1bfT);
    gemm1_kernel<<<(N_NODES + 127) / 128, 512, 0, stream>>>(
        h, emb, W1bfT, a_src1, a_dst1, xp1, es1, ed1, denom1);
    edgeA_kernel<<<EBLK, 256, 0, stream>>>(
        ei, umask, es1, ed1, deg, bcnt, qsrc, qdst, qw);
    bsum_kernel<<<NBLK, 256, 0, stream>>>(deg, bsum);
    bscan_kernel<<<1, 512, 0, stream>>>(bsum, bscan, rowptr);
    rowptr_kernel<<<NBLK, 256, 0, stream>>>(deg, bscan, rowptr);
    scatterB_kernel<<<512, 256, 0, stream>>>(
        qsrc, qdst, qw, bcnt, rowptr, fill, esrc, ew);
    gather1_kernel<<<(N_NODES + 3) / 4, 256, 0, stream>>>(
        xp1, denom1, rowptr, esrc, ew, b1, W2, xp2);
    final2_kernel<<<NBLK, 256, 0, stream>>>(
        xp2, rowptr, esrc, a_src2, a_dst2, b2, out);
}